// Round 5
// baseline (295.446 us; speedup 1.0000x reference)
//
#include <hip/hip_runtime.h>
#include <hip/hip_bf16.h>

#define IN_C  128
#define HID_C 128
#define OUT_CC 64
#define BK    128           // nodes per bucket (dst >> 7)
#define CAPLG 12            // bucket capacity 4096 edges (mean 2046, >40 sigma)

using short8  = __attribute__((ext_vector_type(8))) short;
using float4v = __attribute__((ext_vector_type(4))) float;

// fp32 -> bf16 (round-to-nearest-even, finite inputs)
__device__ __forceinline__ unsigned short f2b(float f) {
    unsigned int u = __float_as_uint(f);
    return (unsigned short)((u + 0x7fffu + ((u >> 16) & 1u)) >> 16);
}
__device__ __forceinline__ unsigned int pack2(float a, float b) {
    return (unsigned int)f2b(a) | ((unsigned int)f2b(b) << 16);
}
__device__ __forceinline__ float2 bf2_to_f2(unsigned int v) {
    float2 r;
    r.x = __uint_as_float(v << 16);
    r.y = __uint_as_float(v & 0xffff0000u);
    return r;
}

// ---- ws layout (bytes) ----
// bfill     int[391]       @ 64         (zeroed via hipMemsetAsync below)
// gbins     int[64]        @ 1664       (degree histogram, zeroed by same memset)
// binfill   int[64]        @ 1920       (scatter ranks, zeroed by same memset)
// begend    int2[N]        @ 4096       (ends 404,096)
// dinv      float[N]       @ 404480     (ends 604,480)
// w1frag    bf16[16384]    @ 604672
// w2frag    bf16[8192]     @ 637440
// ebuf      int[391*4096]  @ 655360     (packed src|dlocal<<20; ends 7,061,504)
// col       int[391*4096]  @ 7061504    (ends 13,467,648)
// h (bf16)  [N*128]        @ 13467904   (pre-scaled by dinv[row]; ends 26,267,904)
// h2(bf16)  [N*64]         @ 26267904   (pre-scaled by dinv[row]; ends 32,667,904)
// perm      int[N]         @ 32668160   (nodes sorted by degree; ends 32,868,160)

// ---------------- fused: edge partition (blocks < NCHK) | weight prep (rest) --------
__global__ __launch_bounds__(256) void k_bpart(const int* __restrict__ ei,
                                               int* __restrict__ bfill,
                                               int* __restrict__ ebuf, int E, int NBK,
                                               int NCHK,
                                               const float* __restrict__ W1,
                                               const float* __restrict__ W2,
                                               unsigned short* __restrict__ w1f,
                                               unsigned short* __restrict__ w2f) {
    const int t = threadIdx.x;
    if ((int)blockIdx.x >= NCHK) {                   // ---- weight prep blocks ----
        int e = ((int)blockIdx.x - NCHK) * 256 + t;
        if (e < 16384) {                             // W1: frag ((nt*4+ks)*64+lane)*8+j
            int j = e & 7, lane = (e >> 3) & 63, ks = (e >> 9) & 3, nt = e >> 11;
            int k = ks * 32 + ((lane >> 4) << 3) + j;
            int n = nt * 16 + (lane & 15);
            w1f[e] = f2b(W1[k * 128 + n]);
        } else if (e < 16384 + 8192) {
            int e2 = e - 16384;
            int j = e2 & 7, lane = (e2 >> 3) & 63, ks = (e2 >> 9) & 3, nt = e2 >> 11;
            int k = ks * 32 + ((lane >> 4) << 3) + j;
            int n = nt * 16 + (lane & 15);
            w2f[e2] = f2b(W2[k * 64 + n]);
        }
        return;
    }
    __shared__ int lh[512];
    __shared__ int lbase[512];
    __shared__ int s_st;
    for (int i = t; i < NBK; i += 256) lh[i] = 0;
    if (t < 64) {                                    // dtype probe (int64 vs int32)
        int ev = ei[2 * t], od = ei[2 * t + 1];
        unsigned long long onz = __ballot(od != 0);
        unsigned long long enz = __ballot(ev != 0);
        if (t == 0) s_st = (onz == 0ull && enz != 0ull) ? 2 : 1;
    }
    __syncthreads();
    const int st = s_st;
    const int base = blockIdx.x * 2048;
    int s[8], d[8];
    #pragma unroll
    for (int j = 0; j < 8; ++j) {
        int i = base + j * 256 + t;
        if (i < E) {
            s[j] = ei[(size_t)st * i];
            d[j] = ei[(size_t)st * ((size_t)E + i)];
            atomicAdd(&lh[d[j] >> 7], 1);
        } else d[j] = -1;
    }
    __syncthreads();
    for (int i = t; i < NBK; i += 256) {
        int c = lh[i];
        lbase[i] = c ? atomicAdd(&bfill[i], c) : 0;
        lh[i] = 0;                                   // becomes local rank counter
    }
    __syncthreads();
    #pragma unroll
    for (int j = 0; j < 8; ++j) {
        if (d[j] >= 0) {
            int b = d[j] >> 7;
            int r = lbase[b] + atomicAdd(&lh[b], 1);
            if (r < (1 << CAPLG))                    // statistical safety clamp
                ebuf[(b << CAPLG) + r] = s[j] | ((d[j] & (BK - 1)) << 20);
        }
    }
}

// ---------------- fused: per-bucket local CSR (blocks < NBK) | MFMA GEMM1 (rest) ----
// CSR blocks additionally accumulate a global degree histogram (64 bins) via a
// per-block LDS histogram, for the degree-balancing permutation.
__global__ __launch_bounds__(256) void k_blmg1(const int* __restrict__ ebuf,
                                               const int* __restrict__ bfill,
                                               int2* __restrict__ begend,
                                               float* __restrict__ dinv,
                                               int* __restrict__ col,
                                               const float* __restrict__ x,
                                               const unsigned short* __restrict__ w1f,
                                               unsigned short* __restrict__ h,
                                               int* __restrict__ gbins,
                                               int N, int NBK) {
    __shared__ unsigned short lds[64 * 136];          // 17.4 KB, shared by both paths
    __shared__ int cnt64[64];                         // GEMM path: local row degrees
    const int t = threadIdx.x;

    if ((int)blockIdx.x < NBK) {
        // ---- per-bucket CSR build ----
        int* cnt   = (int*)lds;
        int* sc    = cnt + BK;
        int* off   = sc + BK;
        int* lbins = off + BK;                       // 64-bin degree histogram
        const int n0 = blockIdx.x * BK;
        const int beg = (int)blockIdx.x << CAPLG;
        const int ecnt = min(bfill[blockIdx.x], 1 << CAPLG);
        if (t < BK) cnt[t] = 0;
        __syncthreads();
        for (int i = t; i < ecnt; i += 256)
            atomicAdd(&cnt[ebuf[beg + i] >> 20], 1);
        __syncthreads();
        if (t < BK) sc[t] = cnt[t];
        __syncthreads();
        for (int o = 1; o < BK; o <<= 1) {
            int v = (t < BK && t >= o) ? sc[t - o] : 0;
            __syncthreads();
            if (t < BK) sc[t] += v;
            __syncthreads();
        }
        int mydeg = -1;
        if (t < BK) {
            int c = cnt[t];
            off[t] = sc[t] - c;                      // exclusive prefix
            if (n0 + t < N) {
                begend[n0 + t] = make_int2(beg + off[t], beg + sc[t]);
                dinv[n0 + t] = rsqrtf((float)c + 1.0f);
                mydeg = min(c, 63);
            }
            cnt[t] = 0;                              // becomes fill counter
        }
        if (t >= 128 && t < 192) lbins[t - 128] = 0;
        __syncthreads();
        if (mydeg >= 0) atomicAdd(&lbins[mydeg], 1);
        for (int i = t; i < ecnt; i += 256) {
            int e = ebuf[beg + i];
            int dl = e >> 20;
            int p = beg + off[dl] + atomicAdd(&cnt[dl], 1);
            col[p] = e & 0xFFFFF;
        }
        __syncthreads();
        if (t < 64 && lbins[t]) atomicAdd(&gbins[t], lbins[t]);
        return;
    }

    // ---- MFMA GEMM1 tile ----
    const int tile = (int)blockIdx.x - NBK;
    const int row0 = tile * 64;
    const int bkt  = row0 >> 7;                       // owning bucket
    const int half = (row0 >> 6) & 1;                 // which 64-row half of the bucket
    if (t < 64) cnt64[t] = 0;
    __syncthreads();
    {   // local degree histogram: scan bucket's packed edges, filter to our half
        const int ebeg = bkt << CAPLG;
        const int ecnt = min(bfill[bkt], 1 << CAPLG);
        for (int i = t; i < ecnt; i += 256) {
            int dl = ebuf[ebeg + i] >> 20;
            if ((dl >> 6) == half) atomicAdd(&cnt64[dl & 63], 1);
        }
    }
    {   // stage x tile to LDS as bf16
        int r = t >> 2, cc = (t & 3) * 32;
        int grow = row0 + r;
        unsigned int* dst = (unsigned int*)&lds[r * 136 + cc];
        if (grow < N) {
            const float4* src = (const float4*)(x + (size_t)grow * 128 + cc);
            #pragma unroll
            for (int i = 0; i < 8; ++i) {
                float4 v = src[i];
                dst[2 * i]     = pack2(v.x, v.y);
                dst[2 * i + 1] = pack2(v.z, v.w);
            }
        } else {
            #pragma unroll
            for (int i = 0; i < 16; ++i) dst[i] = 0;
        }
    }
    __syncthreads();
    const int w = t >> 6, lane = t & 63;
    const int quad = lane >> 4, m = lane & 15;
    short8 a[4];
    #pragma unroll
    for (int ks = 0; ks < 4; ++ks)
        a[ks] = *(const short8*)&lds[(w * 16 + m) * 136 + ks * 32 + quad * 8];
    float4v acc[8];
    #pragma unroll
    for (int nt = 0; nt < 8; ++nt) acc[nt] = (float4v){0.f, 0.f, 0.f, 0.f};
    const short8* wf = (const short8*)w1f;
    #pragma unroll
    for (int nt = 0; nt < 8; ++nt)
        #pragma unroll
        for (int ks = 0; ks < 4; ++ks)
            acc[nt] = __builtin_amdgcn_mfma_f32_16x16x32_bf16(a[ks], wf[(nt * 4 + ks) * 64 + lane],
                                                              acc[nt], 0, 0, 0);
    float drr[4];
    #pragma unroll
    for (int r = 0; r < 4; ++r) {
        int lr = w * 16 + quad * 4 + r;               // local row in tile
        drr[r] = rsqrtf((float)cnt64[lr] + 1.0f);
    }
    #pragma unroll
    for (int nt = 0; nt < 8; ++nt)
        #pragma unroll
        for (int r = 0; r < 4; ++r) {
            int grow = row0 + w * 16 + quad * 4 + r;   // C/D: col=lane&15, row=quad*4+reg
            if (grow < N) h[(size_t)grow * 128 + nt * 16 + m] = f2b(acc[nt][r] * drr[r]);
        }
}

// ---------------- degree-balancing permutation: counting-sort nodes by degree -------
// Each block redundantly prefix-sums the 64-bin histogram, then scatters its 128
// nodes to perm[] by (bin base + atomic rank). Runs after k_blmg1, before aggs.
__global__ __launch_bounds__(128) void k_perm(const int2* __restrict__ begend,
                                              const int* __restrict__ gbins,
                                              int* __restrict__ binfill,
                                              int* __restrict__ perm, int N) {
    __shared__ int boff[64];
    const int t = threadIdx.x;
    if (t == 0) {
        int s = 0;
        #pragma unroll
        for (int i = 0; i < 64; ++i) { int c = gbins[i]; boff[i] = s; s += c; }
    }
    __syncthreads();
    int node = blockIdx.x * 128 + t;
    if (node < N) {
        int2 be = begend[node];
        int dg = min(be.y - be.x, 63);
        int r = boff[dg] + atomicAdd(&binfill[dg], 1);
        perm[r] = node;
    }
}

#define ACC16(u) { float2 q; \
    q = bf2_to_f2(u.x); a0 += q.x; a1 += q.y; \
    q = bf2_to_f2(u.y); a2 += q.x; a3 += q.y; \
    q = bf2_to_f2(u.z); a4 += q.x; a5 += q.y; \
    q = bf2_to_f2(u.w); a6 += q.x; a7 += q.y; }

// 2-stage pipelined gather-sum over [e,end): col indices prefetched one quad ahead.
#define PIPE_GATHER(FEATP, ROWSTRIDE, LANEOFF) \
    int c0, c1, c2, c3; \
    if (e + 4 <= end) { c0 = col[e]; c1 = col[e + 1]; c2 = col[e + 2]; c3 = col[e + 3]; } \
    for (; e + 8 <= end; e += 4) { \
        int p0 = col[e + 4], p1 = col[e + 5], p2 = col[e + 6], p3 = col[e + 7]; \
        uint4 u0 = FEATP[(size_t)c0 * ROWSTRIDE + LANEOFF]; \
        uint4 u1 = FEATP[(size_t)c1 * ROWSTRIDE + LANEOFF]; \
        uint4 u2 = FEATP[(size_t)c2 * ROWSTRIDE + LANEOFF]; \
        uint4 u3 = FEATP[(size_t)c3 * ROWSTRIDE + LANEOFF]; \
        ACC16(u0) ACC16(u1) ACC16(u2) ACC16(u3) \
        c0 = p0; c1 = p1; c2 = p2; c3 = p3; \
    } \
    if (e + 4 <= end) { \
        uint4 u0 = FEATP[(size_t)c0 * ROWSTRIDE + LANEOFF]; \
        uint4 u1 = FEATP[(size_t)c1 * ROWSTRIDE + LANEOFF]; \
        uint4 u2 = FEATP[(size_t)c2 * ROWSTRIDE + LANEOFF]; \
        uint4 u3 = FEATP[(size_t)c3 * ROWSTRIDE + LANEOFF]; \
        ACC16(u0) ACC16(u1) ACC16(u2) ACC16(u3) \
        e += 4; \
    } \
    for (; e < end; ++e) { \
        uint4 u = FEATP[(size_t)col[e] * ROWSTRIDE + LANEOFF]; \
        ACC16(u) \
    }

// ---------------- fused agg layer 1 + bias + ReLU + GEMM2 (h2 = h1 @ W2, pre-scaled) ----
// Nodes visited in degree-sorted order via perm[] so all 16 nodes of a block have
// ~equal degree (no divergence waste, minimal barrier wait before the epilogue).
__global__ __launch_bounds__(256) void k_aggmg2(const uint4* __restrict__ feat,
                                                const int2* __restrict__ begend,
                                                const int* __restrict__ col,
                                                const float* __restrict__ dinv,
                                                const float* __restrict__ b1,
                                                const unsigned short* __restrict__ w2f,
                                                const int* __restrict__ perm,
                                                unsigned short* __restrict__ h2, int N) {
    __shared__ unsigned short lds[16 * 136];           // 16 h1 rows, stride 136 bf16
    __shared__ float dvs[16];                          // dinv of the 16 nodes
    __shared__ int   pn[16];                           // original node IDs (-1 pad)
    const int grp = threadIdx.x >> 4;                  // 16 groups per block
    const int l16 = threadIdx.x & 15;
    const int slot = blockIdx.x * 16 + grp;
    const int node = (slot < N) ? perm[slot] : -1;
    float a0 = 0.f, a1 = 0.f, a2 = 0.f, a3 = 0.f, a4 = 0.f, a5 = 0.f, a6 = 0.f, a7 = 0.f;
    if (node >= 0) {
        const float dd = dinv[node];
        if (l16 == 0) { dvs[grp] = dd; pn[grp] = node; }
        const int2 be = begend[node];
        int e = be.x; const int end = be.y;
        {
            uint4 sv = feat[(size_t)node * 16 + l16];  // self-loop (row already * dinv[node])
            float2 q;
            q = bf2_to_f2(sv.x); a0 = q.x; a1 = q.y;
            q = bf2_to_f2(sv.y); a2 = q.x; a3 = q.y;
            q = bf2_to_f2(sv.z); a4 = q.x; a5 = q.y;
            q = bf2_to_f2(sv.w); a6 = q.x; a7 = q.y;
        }
        PIPE_GATHER(feat, 16, l16)
        float4 ba = ((const float4*)b1)[2 * l16];
        float4 bb = ((const float4*)b1)[2 * l16 + 1];
        a0 = fmaxf(a0 * dd + ba.x, 0.0f);
        a1 = fmaxf(a1 * dd + ba.y, 0.0f);
        a2 = fmaxf(a2 * dd + ba.z, 0.0f);
        a3 = fmaxf(a3 * dd + ba.w, 0.0f);
        a4 = fmaxf(a4 * dd + bb.x, 0.0f);
        a5 = fmaxf(a5 * dd + bb.y, 0.0f);
        a6 = fmaxf(a6 * dd + bb.z, 0.0f);
        a7 = fmaxf(a7 * dd + bb.w, 0.0f);
    } else if (l16 == 0) { dvs[grp] = 0.f; pn[grp] = -1; }
    {   // stage h1 row to LDS (bf16)
        uint4 o;
        o.x = pack2(a0, a1);
        o.y = pack2(a2, a3);
        o.z = pack2(a4, a5);
        o.w = pack2(a6, a7);
        *(uint4*)&lds[grp * 136 + l16 * 8] = o;
    }
    __syncthreads();
    // ---- MFMA GEMM2 epilogue: 16x128 @ 128x64; wave w computes output col-tile w ----
    const int w = threadIdx.x >> 6, lane = threadIdx.x & 63;
    const int quad = lane >> 4, m = lane & 15;
    short8 a[4];
    #pragma unroll
    for (int ks = 0; ks < 4; ++ks)
        a[ks] = *(const short8*)&lds[m * 136 + ks * 32 + quad * 8];
    float4v acc = (float4v){0.f, 0.f, 0.f, 0.f};
    const short8* wf = (const short8*)w2f;
    #pragma unroll
    for (int ks = 0; ks < 4; ++ks)
        acc = __builtin_amdgcn_mfma_f32_16x16x32_bf16(a[ks], wf[(w * 4 + ks) * 64 + lane],
                                                      acc, 0, 0, 0);
    #pragma unroll
    for (int r = 0; r < 4; ++r) {
        int gn = pn[quad * 4 + r];                    // C/D: col=lane&15, row=quad*4+reg
        if (gn >= 0) h2[(size_t)gn * 64 + w * 16 + m] = f2b(acc[r] * dvs[quad * 4 + r]);
    }
}

// ---------------- agg layer 2: one node per 8 lanes (uint4 gathers), +b2, fp32 out ----
__global__ __launch_bounds__(256) void k_agg64(const uint4* __restrict__ feat,
                                               const int2* __restrict__ begend,
                                               const int* __restrict__ col,
                                               const float* __restrict__ dinv,
                                               const float* __restrict__ bias,
                                               const int* __restrict__ perm,
                                               float* __restrict__ out, int N) {
    const int grp = threadIdx.x >> 3;                  // 32 nodes per block
    const int l8  = threadIdx.x & 7;
    const int slot = blockIdx.x * 32 + grp;
    if (slot >= N) return;
    const int node = perm[slot];
    const float dd = dinv[node];
    const int2 be = begend[node];
    int e = be.x; const int end = be.y;
    float a0, a1, a2, a3, a4, a5, a6, a7;
    {
        uint4 sv = feat[(size_t)node * 8 + l8];        // self-loop (pre-scaled)
        float2 q;
        q = bf2_to_f2(sv.x); a0 = q.x; a1 = q.y;
        q = bf2_to_f2(sv.y); a2 = q.x; a3 = q.y;
        q = bf2_to_f2(sv.z); a4 = q.x; a5 = q.y;
        q = bf2_to_f2(sv.w); a6 = q.x; a7 = q.y;
    }
    PIPE_GATHER(feat, 8, l8)
    float4 ba = ((const float4*)bias)[2 * l8];
    float4 bb = ((const float4*)bias)[2 * l8 + 1];
    float4 o1, o2;
    o1.x = a0 * dd + ba.x;
    o1.y = a1 * dd + ba.y;
    o1.z = a2 * dd + ba.z;
    o1.w = a3 * dd + ba.w;
    o2.x = a4 * dd + bb.x;
    o2.y = a5 * dd + bb.y;
    o2.z = a6 * dd + bb.z;
    o2.w = a7 * dd + bb.w;
    float4* op = (float4*)out + (size_t)node * 16 + 2 * l8;
    op[0] = o1;
    op[1] = o2;
}

extern "C" void kernel_launch(void* const* d_in, const int* in_sizes, int n_in,
                              void* d_out, int out_size, void* d_ws, size_t ws_size,
                              hipStream_t stream) {
    const float* x  = (const float*)d_in[0];
    const int*   ei = (const int*)d_in[1];
    const float* W1 = (const float*)d_in[2];
    const float* b1 = (const float*)d_in[3];
    const float* W2 = (const float*)d_in[4];
    const float* b2 = (const float*)d_in[5];

    const int N = in_sizes[0] / IN_C;               // 50000
    const int E = in_sizes[1] / 2;                  // 800000
    const int NBK  = (N + BK - 1) / BK;             // 391 buckets
    const int NCHK = (E + 2047) / 2048;             // 391 edge chunks
    const int NT1  = (N + 63) / 64;                 // 782 GEMM tiles
    const int NPB  = (N + 127) / 128;               // perm blocks

    char* ws = (char*)d_ws;
    int*            bfill   = (int*)(ws + 64);
    int*            gbins   = (int*)(ws + 1664);
    int*            binfill = (int*)(ws + 1920);
    int2*           begend  = (int2*)(ws + 4096);
    float*          dinv    = (float*)(ws + 404480);
    unsigned short* w1f     = (unsigned short*)(ws + 604672);
    unsigned short* w2f     = (unsigned short*)(ws + 637440);
    int*            ebuf    = (int*)(ws + 655360);               // NBK<<CAPLG packed ints
    int*            col     = (int*)(ws + 7061504);
    unsigned short* h       = (unsigned short*)(ws + 13467904);  // bf16 [N,128], pre-scaled
    unsigned short* h2      = (unsigned short*)(ws + 26267904);  // bf16 [N,64], pre-scaled
    int*            perm    = (int*)(ws + 32668160);             // int[N]

    // ---- zero bfill + gbins + binfill (graph-capture-legal async memset) ----
    hipMemsetAsync(ws + 64, 0, 4032, stream);

    // ---- fused: edge partition + dtype probe | weight prep ----
    k_bpart<<<NCHK + 96, 256, 0, stream>>>(ei, bfill, ebuf, E, NBK, NCHK,
                                           W1, W2, w1f, w2f);

    // ---- fused: bucket-local CSR finalize (+deg histogram) + GEMM1 (pre-scaled h) ----
    k_blmg1<<<NBK + NT1, 256, 0, stream>>>(ebuf, bfill, begend, dinv, col,
                                           x, w1f, h, gbins, N, NBK);

    // ---- degree-balancing permutation (counting sort, 64 bins) ----
    k_perm<<<NPB, 128, 0, stream>>>(begend, gbins, binfill, perm, N);

    // ---- fused layer-1 aggregation (+b1, ReLU) + GEMM2 MFMA epilogue ----
    k_aggmg2<<<(N + 15) / 16, 256, 0, stream>>>((const uint4*)h, begend, col, dinv, b1,
                                                w2f, perm, h2, N);

    // ---- layer 2 aggregation (+b2, fp32 out) ----
    k_agg64<<<(N + 31) / 32, 256, 0, stream>>>((const uint4*)h2, begend, col, dinv, b2,
                                               perm, (float*)d_out, N);
}

// Round 6
// 170.230 us; speedup vs baseline: 1.7356x; 1.7356x over previous
//
#include <hip/hip_runtime.h>
#include <hip/hip_bf16.h>

#define IN_C  128
#define HID_C 128
#define OUT_CC 64
#define BK    128           // nodes per bucket (dst >> 7)
#define CAPLG 12            // bucket capacity 4096 edges (mean 2046, >40 sigma)

using short8  = __attribute__((ext_vector_type(8))) short;
using float4v = __attribute__((ext_vector_type(4))) float;

// fp32 -> bf16 (round-to-nearest-even, finite inputs)
__device__ __forceinline__ unsigned short f2b(float f) {
    unsigned int u = __float_as_uint(f);
    return (unsigned short)((u + 0x7fffu + ((u >> 16) & 1u)) >> 16);
}
__device__ __forceinline__ unsigned int pack2(float a, float b) {
    return (unsigned int)f2b(a) | ((unsigned int)f2b(b) << 16);
}
__device__ __forceinline__ float2 bf2_to_f2(unsigned int v) {
    float2 r;
    r.x = __uint_as_float(v << 16);
    r.y = __uint_as_float(v & 0xffff0000u);
    return r;
}

// ---- ws layout (bytes) ----
// bfill     int[391]       @ 64         (zeroed via hipMemsetAsync)
// begend    int2[N]        @ 4096       (ends 404,096)
// dinv      float[N]       @ 404480     (ends 604,480)
// w1frag    bf16[16384]    @ 604672
// w2frag    bf16[8192]     @ 637440
// ebuf      int[391*4096]  @ 655360     (packed src|dlocal<<20; ends 7,061,504)
// col       int[391*4096]  @ 7061504    (ends 13,467,648)
// h (bf16)  [N*128]        @ 13467904   (pre-scaled by dinv[row]; ends 26,267,904)
// h2(bf16)  [N*64]         @ 26267904   (pre-scaled by dinv[row]; ends 32,667,904)
// perm      int[N]         @ 32668160   (within-bucket degree-sorted node order)

// ---------------- fused: edge partition (blocks < NCHK) | weight prep (rest) --------
__global__ __launch_bounds__(256) void k_bpart(const int* __restrict__ ei,
                                               int* __restrict__ bfill,
                                               int* __restrict__ ebuf, int E, int NBK,
                                               int NCHK,
                                               const float* __restrict__ W1,
                                               const float* __restrict__ W2,
                                               unsigned short* __restrict__ w1f,
                                               unsigned short* __restrict__ w2f) {
    const int t = threadIdx.x;
    if ((int)blockIdx.x >= NCHK) {                   // ---- weight prep blocks ----
        int e = ((int)blockIdx.x - NCHK) * 256 + t;
        if (e < 16384) {                             // W1: frag ((nt*4+ks)*64+lane)*8+j
            int j = e & 7, lane = (e >> 3) & 63, ks = (e >> 9) & 3, nt = e >> 11;
            int k = ks * 32 + ((lane >> 4) << 3) + j;
            int n = nt * 16 + (lane & 15);
            w1f[e] = f2b(W1[k * 128 + n]);
        } else if (e < 16384 + 8192) {
            int e2 = e - 16384;
            int j = e2 & 7, lane = (e2 >> 3) & 63, ks = (e2 >> 9) & 3, nt = e2 >> 11;
            int k = ks * 32 + ((lane >> 4) << 3) + j;
            int n = nt * 16 + (lane & 15);
            w2f[e2] = f2b(W2[k * 64 + n]);
        }
        return;
    }
    __shared__ int lh[512];
    __shared__ int lbase[512];
    __shared__ int s_st;
    for (int i = t; i < NBK; i += 256) lh[i] = 0;
    if (t < 64) {                                    // dtype probe (int64 vs int32)
        int ev = ei[2 * t], od = ei[2 * t + 1];
        unsigned long long onz = __ballot(od != 0);
        unsigned long long enz = __ballot(ev != 0);
        if (t == 0) s_st = (onz == 0ull && enz != 0ull) ? 2 : 1;
    }
    __syncthreads();
    const int st = s_st;
    const int base = blockIdx.x * 2048;
    int s[8], d[8];
    #pragma unroll
    for (int j = 0; j < 8; ++j) {
        int i = base + j * 256 + t;
        if (i < E) {
            s[j] = ei[(size_t)st * i];
            d[j] = ei[(size_t)st * ((size_t)E + i)];
            atomicAdd(&lh[d[j] >> 7], 1);
        } else d[j] = -1;
    }
    __syncthreads();
    for (int i = t; i < NBK; i += 256) {
        int c = lh[i];
        lbase[i] = c ? atomicAdd(&bfill[i], c) : 0;
        lh[i] = 0;                                   // becomes local rank counter
    }
    __syncthreads();
    #pragma unroll
    for (int j = 0; j < 8; ++j) {
        if (d[j] >= 0) {
            int b = d[j] >> 7;
            int r = lbase[b] + atomicAdd(&lh[b], 1);
            if (r < (1 << CAPLG))                    // statistical safety clamp
                ebuf[(b << CAPLG) + r] = s[j] | ((d[j] & (BK - 1)) << 20);
        }
    }
}

// ---------------- fused: per-bucket local CSR (blocks < NBK) | MFMA GEMM1 (rest) ----
// CSR blocks additionally counting-sort their 128 nodes by degree WITHIN the bucket
// (LDS only, no global atomics) producing perm[] so agg waves see uniform degrees.
__global__ __launch_bounds__(256) void k_blmg1(const int* __restrict__ ebuf,
                                               const int* __restrict__ bfill,
                                               int2* __restrict__ begend,
                                               float* __restrict__ dinv,
                                               int* __restrict__ col,
                                               const float* __restrict__ x,
                                               const unsigned short* __restrict__ w1f,
                                               unsigned short* __restrict__ h,
                                               int* __restrict__ perm,
                                               int N, int NBK) {
    __shared__ unsigned short lds[64 * 136];          // 17.4 KB, shared by both paths
    __shared__ int cnt64[64];                         // GEMM path: local row degrees
    const int t = threadIdx.x;

    if ((int)blockIdx.x < NBK) {
        // ---- per-bucket CSR build + within-bucket degree sort ----
        int* cnt  = (int*)lds;
        int* sc   = cnt + BK;
        int* off  = sc + BK;
        int* bins = off + BK;                        // 64-bin degree histogram
        int* boff = bins + 64;                       // inclusive prefix of bins
        const int n0 = blockIdx.x * BK;
        const int beg = (int)blockIdx.x << CAPLG;
        const int ecnt = min(bfill[blockIdx.x], 1 << CAPLG);
        if (t < BK) cnt[t] = 0;
        if (t >= 128 && t < 192) bins[t - 128] = 0;
        __syncthreads();
        for (int i = t; i < ecnt; i += 256)
            atomicAdd(&cnt[ebuf[beg + i] >> 20], 1);
        __syncthreads();
        if (t < BK) sc[t] = cnt[t];
        __syncthreads();
        for (int o = 1; o < BK; o <<= 1) {
            int v = (t < BK && t >= o) ? sc[t - o] : 0;
            __syncthreads();
            if (t < BK) sc[t] += v;
            __syncthreads();
        }
        int mydeg = -1;
        if (t < BK) {
            int c = cnt[t];
            off[t] = sc[t] - c;                      // exclusive prefix
            if (n0 + t < N) {
                begend[n0 + t] = make_int2(beg + off[t], beg + sc[t]);
                dinv[n0 + t] = rsqrtf((float)c + 1.0f);
                mydeg = min(c, 63);
            }
            cnt[t] = 0;                              // becomes fill counter
        }
        __syncthreads();
        if (mydeg >= 0) atomicAdd(&bins[mydeg], 1);
        for (int i = t; i < ecnt; i += 256) {
            int e = ebuf[beg + i];
            int dl = e >> 20;
            int p = beg + off[dl] + atomicAdd(&cnt[dl], 1);
            col[p] = e & 0xFFFFF;
        }
        __syncthreads();
        // 64-bin prefix (Hillis-Steele, inclusive) then scatter node IDs to perm
        if (t < 64) boff[t] = bins[t];
        __syncthreads();
        for (int o = 1; o < 64; o <<= 1) {
            int v = (t < 64 && t >= o) ? boff[t - o] : 0;
            __syncthreads();
            if (t < 64) boff[t] += v;
            __syncthreads();
        }
        if (t < 64) sc[t] = 0;                       // per-bin fill counters
        __syncthreads();
        if (mydeg >= 0) {
            int r = boff[mydeg] - bins[mydeg] + atomicAdd(&sc[mydeg], 1);
            perm[n0 + r] = n0 + t;
        }
        return;
    }

    // ---- MFMA GEMM1 tile ----
    const int tile = (int)blockIdx.x - NBK;
    const int row0 = tile * 64;
    const int bkt  = row0 >> 7;                       // owning bucket
    const int half = (row0 >> 6) & 1;                 // which 64-row half of the bucket
    if (t < 64) cnt64[t] = 0;
    __syncthreads();
    {   // local degree histogram: scan bucket's packed edges, filter to our half
        const int ebeg = bkt << CAPLG;
        const int ecnt = min(bfill[bkt], 1 << CAPLG);
        for (int i = t; i < ecnt; i += 256) {
            int dl = ebuf[ebeg + i] >> 20;
            if ((dl >> 6) == half) atomicAdd(&cnt64[dl & 63], 1);
        }
    }
    {   // stage x tile to LDS as bf16
        int r = t >> 2, cc = (t & 3) * 32;
        int grow = row0 + r;
        unsigned int* dst = (unsigned int*)&lds[r * 136 + cc];
        if (grow < N) {
            const float4* src = (const float4*)(x + (size_t)grow * 128 + cc);
            #pragma unroll
            for (int i = 0; i < 8; ++i) {
                float4 v = src[i];
                dst[2 * i]     = pack2(v.x, v.y);
                dst[2 * i + 1] = pack2(v.z, v.w);
            }
        } else {
            #pragma unroll
            for (int i = 0; i < 16; ++i) dst[i] = 0;
        }
    }
    __syncthreads();
    const int w = t >> 6, lane = t & 63;
    const int quad = lane >> 4, m = lane & 15;
    short8 a[4];
    #pragma unroll
    for (int ks = 0; ks < 4; ++ks)
        a[ks] = *(const short8*)&lds[(w * 16 + m) * 136 + ks * 32 + quad * 8];
    float4v acc[8];
    #pragma unroll
    for (int nt = 0; nt < 8; ++nt) acc[nt] = (float4v){0.f, 0.f, 0.f, 0.f};
    const short8* wf = (const short8*)w1f;
    #pragma unroll
    for (int nt = 0; nt < 8; ++nt)
        #pragma unroll
        for (int ks = 0; ks < 4; ++ks)
            acc[nt] = __builtin_amdgcn_mfma_f32_16x16x32_bf16(a[ks], wf[(nt * 4 + ks) * 64 + lane],
                                                              acc[nt], 0, 0, 0);
    float drr[4];
    #pragma unroll
    for (int r = 0; r < 4; ++r) {
        int lr = w * 16 + quad * 4 + r;               // local row in tile
        drr[r] = rsqrtf((float)cnt64[lr] + 1.0f);
    }
    #pragma unroll
    for (int nt = 0; nt < 8; ++nt)
        #pragma unroll
        for (int r = 0; r < 4; ++r) {
            int grow = row0 + w * 16 + quad * 4 + r;   // C/D: col=lane&15, row=quad*4+reg
            if (grow < N) h[(size_t)grow * 128 + nt * 16 + m] = f2b(acc[nt][r] * drr[r]);
        }
}

#define ACC16(u) { float2 q; \
    q = bf2_to_f2(u.x); a0 += q.x; a1 += q.y; \
    q = bf2_to_f2(u.y); a2 += q.x; a3 += q.y; \
    q = bf2_to_f2(u.z); a4 += q.x; a5 += q.y; \
    q = bf2_to_f2(u.w); a6 += q.x; a7 += q.y; }

// 2-stage pipelined gather-sum over [e,end): col indices prefetched one quad ahead.
#define PIPE_GATHER(FEATP, ROWSTRIDE, LANEOFF) \
    int c0, c1, c2, c3; \
    if (e + 4 <= end) { c0 = col[e]; c1 = col[e + 1]; c2 = col[e + 2]; c3 = col[e + 3]; } \
    for (; e + 8 <= end; e += 4) { \
        int p0 = col[e + 4], p1 = col[e + 5], p2 = col[e + 6], p3 = col[e + 7]; \
        uint4 u0 = FEATP[(size_t)c0 * ROWSTRIDE + LANEOFF]; \
        uint4 u1 = FEATP[(size_t)c1 * ROWSTRIDE + LANEOFF]; \
        uint4 u2 = FEATP[(size_t)c2 * ROWSTRIDE + LANEOFF]; \
        uint4 u3 = FEATP[(size_t)c3 * ROWSTRIDE + LANEOFF]; \
        ACC16(u0) ACC16(u1) ACC16(u2) ACC16(u3) \
        c0 = p0; c1 = p1; c2 = p2; c3 = p3; \
    } \
    if (e + 4 <= end) { \
        uint4 u0 = FEATP[(size_t)c0 * ROWSTRIDE + LANEOFF]; \
        uint4 u1 = FEATP[(size_t)c1 * ROWSTRIDE + LANEOFF]; \
        uint4 u2 = FEATP[(size_t)c2 * ROWSTRIDE + LANEOFF]; \
        uint4 u3 = FEATP[(size_t)c3 * ROWSTRIDE + LANEOFF]; \
        ACC16(u0) ACC16(u1) ACC16(u2) ACC16(u3) \
        e += 4; \
    } \
    for (; e < end; ++e) { \
        uint4 u = FEATP[(size_t)col[e] * ROWSTRIDE + LANEOFF]; \
        ACC16(u) \
    }

// ---------------- fused agg layer 1 + bias + ReLU + GEMM2 (h2 = h1 @ W2, pre-scaled) ----
// Nodes visited in within-bucket degree-sorted order: all 16 nodes of a block have
// ~equal degree (no divergence waste) and stay in the same 128-node bucket window.
__global__ __launch_bounds__(256) void k_aggmg2(const uint4* __restrict__ feat,
                                                const int2* __restrict__ begend,
                                                const int* __restrict__ col,
                                                const float* __restrict__ dinv,
                                                const float* __restrict__ b1,
                                                const unsigned short* __restrict__ w2f,
                                                const int* __restrict__ perm,
                                                unsigned short* __restrict__ h2, int N) {
    __shared__ unsigned short lds[16 * 136];           // 16 h1 rows, stride 136 bf16
    __shared__ float dvs[16];                          // dinv of the 16 nodes
    __shared__ int   pn[16];                           // original node IDs (-1 pad)
    const int grp = threadIdx.x >> 4;                  // 16 groups per block
    const int l16 = threadIdx.x & 15;
    const int slot = blockIdx.x * 16 + grp;
    const int node = (slot < N) ? perm[slot] : -1;
    float a0 = 0.f, a1 = 0.f, a2 = 0.f, a3 = 0.f, a4 = 0.f, a5 = 0.f, a6 = 0.f, a7 = 0.f;
    if (node >= 0) {
        const float dd = dinv[node];
        if (l16 == 0) { dvs[grp] = dd; pn[grp] = node; }
        const int2 be = begend[node];
        int e = be.x; const int end = be.y;
        {
            uint4 sv = feat[(size_t)node * 16 + l16];  // self-loop (row already * dinv[node])
            float2 q;
            q = bf2_to_f2(sv.x); a0 = q.x; a1 = q.y;
            q = bf2_to_f2(sv.y); a2 = q.x; a3 = q.y;
            q = bf2_to_f2(sv.z); a4 = q.x; a5 = q.y;
            q = bf2_to_f2(sv.w); a6 = q.x; a7 = q.y;
        }
        PIPE_GATHER(feat, 16, l16)
        float4 ba = ((const float4*)b1)[2 * l16];
        float4 bb = ((const float4*)b1)[2 * l16 + 1];
        a0 = fmaxf(a0 * dd + ba.x, 0.0f);
        a1 = fmaxf(a1 * dd + ba.y, 0.0f);
        a2 = fmaxf(a2 * dd + ba.z, 0.0f);
        a3 = fmaxf(a3 * dd + ba.w, 0.0f);
        a4 = fmaxf(a4 * dd + bb.x, 0.0f);
        a5 = fmaxf(a5 * dd + bb.y, 0.0f);
        a6 = fmaxf(a6 * dd + bb.z, 0.0f);
        a7 = fmaxf(a7 * dd + bb.w, 0.0f);
    } else if (l16 == 0) { dvs[grp] = 0.f; pn[grp] = -1; }
    {   // stage h1 row to LDS (bf16)
        uint4 o;
        o.x = pack2(a0, a1);
        o.y = pack2(a2, a3);
        o.z = pack2(a4, a5);
        o.w = pack2(a6, a7);
        *(uint4*)&lds[grp * 136 + l16 * 8] = o;
    }
    __syncthreads();
    // ---- MFMA GEMM2 epilogue: 16x128 @ 128x64; wave w computes output col-tile w ----
    const int w = threadIdx.x >> 6, lane = threadIdx.x & 63;
    const int quad = lane >> 4, m = lane & 15;
    short8 a[4];
    #pragma unroll
    for (int ks = 0; ks < 4; ++ks)
        a[ks] = *(const short8*)&lds[m * 136 + ks * 32 + quad * 8];
    float4v acc = (float4v){0.f, 0.f, 0.f, 0.f};
    const short8* wf = (const short8*)w2f;
    #pragma unroll
    for (int ks = 0; ks < 4; ++ks)
        acc = __builtin_amdgcn_mfma_f32_16x16x32_bf16(a[ks], wf[(w * 4 + ks) * 64 + lane],
                                                      acc, 0, 0, 0);
    #pragma unroll
    for (int r = 0; r < 4; ++r) {
        int gn = pn[quad * 4 + r];                    // C/D: col=lane&15, row=quad*4+reg
        if (gn >= 0) h2[(size_t)gn * 64 + w * 16 + m] = f2b(acc[r] * dvs[quad * 4 + r]);
    }
}

// ---------------- agg layer 2: one node per 8 lanes (uint4 gathers), +b2, fp32 out ----
__global__ __launch_bounds__(256) void k_agg64(const uint4* __restrict__ feat,
                                               const int2* __restrict__ begend,
                                               const int* __restrict__ col,
                                               const float* __restrict__ dinv,
                                               const float* __restrict__ bias,
                                               const int* __restrict__ perm,
                                               float* __restrict__ out, int N) {
    const int grp = threadIdx.x >> 3;                  // 32 nodes per block
    const int l8  = threadIdx.x & 7;
    const int slot = blockIdx.x * 32 + grp;
    if (slot >= N) return;
    const int node = perm[slot];
    const float dd = dinv[node];
    const int2 be = begend[node];
    int e = be.x; const int end = be.y;
    float a0, a1, a2, a3, a4, a5, a6, a7;
    {
        uint4 sv = feat[(size_t)node * 8 + l8];        // self-loop (pre-scaled)
        float2 q;
        q = bf2_to_f2(sv.x); a0 = q.x; a1 = q.y;
        q = bf2_to_f2(sv.y); a2 = q.x; a3 = q.y;
        q = bf2_to_f2(sv.z); a4 = q.x; a5 = q.y;
        q = bf2_to_f2(sv.w); a6 = q.x; a7 = q.y;
    }
    PIPE_GATHER(feat, 8, l8)
    float4 ba = ((const float4*)bias)[2 * l8];
    float4 bb = ((const float4*)bias)[2 * l8 + 1];
    float4 o1, o2;
    o1.x = a0 * dd + ba.x;
    o1.y = a1 * dd + ba.y;
    o1.z = a2 * dd + ba.z;
    o1.w = a3 * dd + ba.w;
    o2.x = a4 * dd + bb.x;
    o2.y = a5 * dd + bb.y;
    o2.z = a6 * dd + bb.z;
    o2.w = a7 * dd + bb.w;
    float4* op = (float4*)out + (size_t)node * 16 + 2 * l8;
    op[0] = o1;
    op[1] = o2;
}

extern "C" void kernel_launch(void* const* d_in, const int* in_sizes, int n_in,
                              void* d_out, int out_size, void* d_ws, size_t ws_size,
                              hipStream_t stream) {
    const float* x  = (const float*)d_in[0];
    const int*   ei = (const int*)d_in[1];
    const float* W1 = (const float*)d_in[2];
    const float* b1 = (const float*)d_in[3];
    const float* W2 = (const float*)d_in[4];
    const float* b2 = (const float*)d_in[5];

    const int N = in_sizes[0] / IN_C;               // 50000
    const int E = in_sizes[1] / 2;                  // 800000
    const int NBK  = (N + BK - 1) / BK;             // 391 buckets
    const int NCHK = (E + 2047) / 2048;             // 391 edge chunks
    const int NT1  = (N + 63) / 64;                 // 782 GEMM tiles

    char* ws = (char*)d_ws;
    int*            bfill   = (int*)(ws + 64);
    int2*           begend  = (int2*)(ws + 4096);
    float*          dinv    = (float*)(ws + 404480);
    unsigned short* w1f     = (unsigned short*)(ws + 604672);
    unsigned short* w2f     = (unsigned short*)(ws + 637440);
    int*            ebuf    = (int*)(ws + 655360);               // NBK<<CAPLG packed ints
    int*            col     = (int*)(ws + 7061504);
    unsigned short* h       = (unsigned short*)(ws + 13467904);  // bf16 [N,128], pre-scaled
    unsigned short* h2      = (unsigned short*)(ws + 26267904);  // bf16 [N,64], pre-scaled
    int*            perm    = (int*)(ws + 32668160);             // int[N]

    // ---- bfill zero (graph-capture-legal async memset) ----
    hipMemsetAsync(bfill, 0, NBK * sizeof(int), stream);

    // ---- fused: edge partition + dtype probe | weight prep ----
    k_bpart<<<NCHK + 96, 256, 0, stream>>>(ei, bfill, ebuf, E, NBK, NCHK,
                                           W1, W2, w1f, w2f);

    // ---- fused: bucket-local CSR finalize (+in-bucket degree sort) + GEMM1 ----
    k_blmg1<<<NBK + NT1, 256, 0, stream>>>(ebuf, bfill, begend, dinv, col,
                                           x, w1f, h, perm, N, NBK);

    // ---- fused layer-1 aggregation (+b1, ReLU) + GEMM2 MFMA epilogue ----
    k_aggmg2<<<(N + 15) / 16, 256, 0, stream>>>((const uint4*)h, begend, col, dinv, b1,
                                                w2f, perm, h2, N);

    // ---- layer 2 aggregation (+b2, fp32 out) ----
    k_agg64<<<(N + 31) / 32, 256, 0, stream>>>((const uint4*)h2, begend, col, dinv, b2,
                                               perm, (float*)d_out, N);
}

// Round 7
// 168.811 us; speedup vs baseline: 1.7502x; 1.0084x over previous
//
#include <hip/hip_runtime.h>
#include <hip/hip_bf16.h>

#define IN_C  128
#define HID_C 128
#define OUT_CC 64
#define BK    128           // nodes per bucket (dst >> 7)
#define CAPLG 12            // bucket capacity 4096 edges (mean 2046, >40 sigma)

using short8  = __attribute__((ext_vector_type(8))) short;
using float4v = __attribute__((ext_vector_type(4))) float;

// fp32 -> bf16 (round-to-nearest-even, finite inputs)
__device__ __forceinline__ unsigned short f2b(float f) {
    unsigned int u = __float_as_uint(f);
    return (unsigned short)((u + 0x7fffu + ((u >> 16) & 1u)) >> 16);
}
__device__ __forceinline__ unsigned int pack2(float a, float b) {
    return (unsigned int)f2b(a) | ((unsigned int)f2b(b) << 16);
}
__device__ __forceinline__ float2 bf2_to_f2(unsigned int v) {
    float2 r;
    r.x = __uint_as_float(v << 16);
    r.y = __uint_as_float(v & 0xffff0000u);
    return r;
}

// ---- ws layout (bytes) ----
// bfill     int[391]       @ 64         (zeroed via hipMemsetAsync)
// begend    int2[N]        @ 4096       (ends 404,096)
// dinv      float[N]       @ 404480     (ends 604,480)
// w1frag    bf16[16384]    @ 604672
// w2frag    bf16[8192]     @ 637440
// ebuf      int[391*4096]  @ 655360     (packed src|dlocal<<20; ends 7,061,504)
// col       int[391*4096]  @ 7061504    (ends 13,467,648)
// h (bf16)  [N*128]        @ 13467904   (pre-scaled by dinv[row]; ends 26,267,904)
// h2(bf16)  [N*64]         @ 26267904   (pre-scaled by dinv[row]; ends 32,667,904)

// ---------------- fused: edge partition (blocks < NCHK) | weight prep (rest) --------
__global__ __launch_bounds__(256) void k_bpart(const int* __restrict__ ei,
                                               int* __restrict__ bfill,
                                               int* __restrict__ ebuf, int E, int NBK,
                                               int NCHK,
                                               const float* __restrict__ W1,
                                               const float* __restrict__ W2,
                                               unsigned short* __restrict__ w1f,
                                               unsigned short* __restrict__ w2f) {
    const int t = threadIdx.x;
    if ((int)blockIdx.x >= NCHK) {                   // ---- weight prep blocks ----
        int e = ((int)blockIdx.x - NCHK) * 256 + t;
        if (e < 16384) {                             // W1: frag ((nt*4+ks)*64+lane)*8+j
            int j = e & 7, lane = (e >> 3) & 63, ks = (e >> 9) & 3, nt = e >> 11;
            int k = ks * 32 + ((lane >> 4) << 3) + j;
            int n = nt * 16 + (lane & 15);
            w1f[e] = f2b(W1[k * 128 + n]);
        } else if (e < 16384 + 8192) {
            int e2 = e - 16384;
            int j = e2 & 7, lane = (e2 >> 3) & 63, ks = (e2 >> 9) & 3, nt = e2 >> 11;
            int k = ks * 32 + ((lane >> 4) << 3) + j;
            int n = nt * 16 + (lane & 15);
            w2f[e2] = f2b(W2[k * 64 + n]);
        }
        return;
    }
    __shared__ int lh[512];
    __shared__ int lbase[512];
    __shared__ int s_st;
    for (int i = t; i < NBK; i += 256) lh[i] = 0;
    if (t < 64) {                                    // dtype probe (int64 vs int32)
        int ev = ei[2 * t], od = ei[2 * t + 1];
        unsigned long long onz = __ballot(od != 0);
        unsigned long long enz = __ballot(ev != 0);
        if (t == 0) s_st = (onz == 0ull && enz != 0ull) ? 2 : 1;
    }
    __syncthreads();
    const int st = s_st;
    const int base = blockIdx.x * 2048;
    int s[8], d[8];
    #pragma unroll
    for (int j = 0; j < 8; ++j) {
        int i = base + j * 256 + t;
        if (i < E) {
            s[j] = ei[(size_t)st * i];
            d[j] = ei[(size_t)st * ((size_t)E + i)];
            atomicAdd(&lh[d[j] >> 7], 1);
        } else d[j] = -1;
    }
    __syncthreads();
    for (int i = t; i < NBK; i += 256) {
        int c = lh[i];
        lbase[i] = c ? atomicAdd(&bfill[i], c) : 0;
        lh[i] = 0;                                   // becomes local rank counter
    }
    __syncthreads();
    #pragma unroll
    for (int j = 0; j < 8; ++j) {
        if (d[j] >= 0) {
            int b = d[j] >> 7;
            int r = lbase[b] + atomicAdd(&lh[b], 1);
            if (r < (1 << CAPLG))                    // statistical safety clamp
                ebuf[(b << CAPLG) + r] = s[j] | ((d[j] & (BK - 1)) << 20);
        }
    }
}

// ---------------- fused: per-bucket local CSR (blocks < NBK) | MFMA GEMM1 (rest) ----
__global__ __launch_bounds__(256) void k_blmg1(const int* __restrict__ ebuf,
                                               const int* __restrict__ bfill,
                                               int2* __restrict__ begend,
                                               float* __restrict__ dinv,
                                               int* __restrict__ col,
                                               const float* __restrict__ x,
                                               const unsigned short* __restrict__ w1f,
                                               unsigned short* __restrict__ h,
                                               int N, int NBK) {
    __shared__ unsigned short lds[64 * 136];          // 17.4 KB, shared by both paths
    __shared__ int cnt64[64];                         // GEMM path: local row degrees
    const int t = threadIdx.x;

    if ((int)blockIdx.x < NBK) {
        // ---- per-bucket CSR build ----
        int* cnt = (int*)lds;
        int* sc  = cnt + BK;
        int* off = sc + BK;
        const int n0 = blockIdx.x * BK;
        const int beg = (int)blockIdx.x << CAPLG;
        const int ecnt = min(bfill[blockIdx.x], 1 << CAPLG);
        if (t < BK) cnt[t] = 0;
        __syncthreads();
        for (int i = t; i < ecnt; i += 256)
            atomicAdd(&cnt[ebuf[beg + i] >> 20], 1);
        __syncthreads();
        if (t < BK) sc[t] = cnt[t];
        __syncthreads();
        for (int o = 1; o < BK; o <<= 1) {
            int v = (t < BK && t >= o) ? sc[t - o] : 0;
            __syncthreads();
            if (t < BK) sc[t] += v;
            __syncthreads();
        }
        if (t < BK) {
            int c = cnt[t];
            off[t] = sc[t] - c;                      // exclusive prefix
            if (n0 + t < N) {
                begend[n0 + t] = make_int2(beg + off[t], beg + sc[t]);
                dinv[n0 + t] = rsqrtf((float)c + 1.0f);
            }
            cnt[t] = 0;                              // becomes fill counter
        }
        __syncthreads();
        for (int i = t; i < ecnt; i += 256) {
            int e = ebuf[beg + i];
            int dl = e >> 20;
            int p = beg + off[dl] + atomicAdd(&cnt[dl], 1);
            col[p] = e & 0xFFFFF;
        }
        return;
    }

    // ---- MFMA GEMM1 tile ----
    const int tile = (int)blockIdx.x - NBK;
    const int row0 = tile * 64;
    const int bkt  = row0 >> 7;                       // owning bucket
    const int half = (row0 >> 6) & 1;                 // which 64-row half of the bucket
    if (t < 64) cnt64[t] = 0;
    __syncthreads();
    {   // local degree histogram: scan bucket's packed edges, filter to our half
        const int ebeg = bkt << CAPLG;
        const int ecnt = min(bfill[bkt], 1 << CAPLG);
        for (int i = t; i < ecnt; i += 256) {
            int dl = ebuf[ebeg + i] >> 20;
            if ((dl >> 6) == half) atomicAdd(&cnt64[dl & 63], 1);
        }
    }
    {   // stage x tile to LDS as bf16
        int r = t >> 2, cc = (t & 3) * 32;
        int grow = row0 + r;
        unsigned int* dst = (unsigned int*)&lds[r * 136 + cc];
        if (grow < N) {
            const float4* src = (const float4*)(x + (size_t)grow * 128 + cc);
            #pragma unroll
            for (int i = 0; i < 8; ++i) {
                float4 v = src[i];
                dst[2 * i]     = pack2(v.x, v.y);
                dst[2 * i + 1] = pack2(v.z, v.w);
            }
        } else {
            #pragma unroll
            for (int i = 0; i < 16; ++i) dst[i] = 0;
        }
    }
    __syncthreads();
    const int w = t >> 6, lane = t & 63;
    const int quad = lane >> 4, m = lane & 15;
    short8 a[4];
    #pragma unroll
    for (int ks = 0; ks < 4; ++ks)
        a[ks] = *(const short8*)&lds[(w * 16 + m) * 136 + ks * 32 + quad * 8];
    float4v acc[8];
    #pragma unroll
    for (int nt = 0; nt < 8; ++nt) acc[nt] = (float4v){0.f, 0.f, 0.f, 0.f};
    const short8* wf = (const short8*)w1f;
    #pragma unroll
    for (int nt = 0; nt < 8; ++nt)
        #pragma unroll
        for (int ks = 0; ks < 4; ++ks)
            acc[nt] = __builtin_amdgcn_mfma_f32_16x16x32_bf16(a[ks], wf[(nt * 4 + ks) * 64 + lane],
                                                              acc[nt], 0, 0, 0);
    float drr[4];
    #pragma unroll
    for (int r = 0; r < 4; ++r) {
        int lr = w * 16 + quad * 4 + r;               // local row in tile
        drr[r] = rsqrtf((float)cnt64[lr] + 1.0f);
    }
    #pragma unroll
    for (int nt = 0; nt < 8; ++nt)
        #pragma unroll
        for (int r = 0; r < 4; ++r) {
            int grow = row0 + w * 16 + quad * 4 + r;   // C/D: col=lane&15, row=quad*4+reg
            if (grow < N) h[(size_t)grow * 128 + nt * 16 + m] = f2b(acc[nt][r] * drr[r]);
        }
}

#define ACC16(u) { float2 q; \
    q = bf2_to_f2(u.x); a0 += q.x; a1 += q.y; \
    q = bf2_to_f2(u.y); a2 += q.x; a3 += q.y; \
    q = bf2_to_f2(u.z); a4 += q.x; a5 += q.y; \
    q = bf2_to_f2(u.w); a6 += q.x; a7 += q.y; }

// 8-wide gather-sum over [e,end): 8 rows in flight per lane as DIRECT loads (no
// register staging/moves), next batch's indices loaded while current accumulates.
// Accumulation strictly in index order -> bitwise identical to the serial loop.
#define PIPE_GATHER8(FEATP, ROWSTRIDE, LANEOFF) \
    int c0, c1, c2, c3, c4, c5, c6, c7; \
    if (e + 8 <= end) { \
        c0 = col[e];     c1 = col[e + 1]; c2 = col[e + 2]; c3 = col[e + 3]; \
        c4 = col[e + 4]; c5 = col[e + 5]; c6 = col[e + 6]; c7 = col[e + 7]; \
    } \
    for (; e + 16 <= end; e += 8) { \
        uint4 u0 = FEATP[(size_t)c0 * ROWSTRIDE + LANEOFF]; \
        uint4 u1 = FEATP[(size_t)c1 * ROWSTRIDE + LANEOFF]; \
        uint4 u2 = FEATP[(size_t)c2 * ROWSTRIDE + LANEOFF]; \
        uint4 u3 = FEATP[(size_t)c3 * ROWSTRIDE + LANEOFF]; \
        uint4 u4 = FEATP[(size_t)c4 * ROWSTRIDE + LANEOFF]; \
        uint4 u5 = FEATP[(size_t)c5 * ROWSTRIDE + LANEOFF]; \
        uint4 u6 = FEATP[(size_t)c6 * ROWSTRIDE + LANEOFF]; \
        uint4 u7 = FEATP[(size_t)c7 * ROWSTRIDE + LANEOFF]; \
        c0 = col[e + 8];  c1 = col[e + 9];  c2 = col[e + 10]; c3 = col[e + 11]; \
        c4 = col[e + 12]; c5 = col[e + 13]; c6 = col[e + 14]; c7 = col[e + 15]; \
        ACC16(u0) ACC16(u1) ACC16(u2) ACC16(u3) \
        ACC16(u4) ACC16(u5) ACC16(u6) ACC16(u7) \
    } \
    if (e + 8 <= end) { \
        uint4 u0 = FEATP[(size_t)c0 * ROWSTRIDE + LANEOFF]; \
        uint4 u1 = FEATP[(size_t)c1 * ROWSTRIDE + LANEOFF]; \
        uint4 u2 = FEATP[(size_t)c2 * ROWSTRIDE + LANEOFF]; \
        uint4 u3 = FEATP[(size_t)c3 * ROWSTRIDE + LANEOFF]; \
        uint4 u4 = FEATP[(size_t)c4 * ROWSTRIDE + LANEOFF]; \
        uint4 u5 = FEATP[(size_t)c5 * ROWSTRIDE + LANEOFF]; \
        uint4 u6 = FEATP[(size_t)c6 * ROWSTRIDE + LANEOFF]; \
        uint4 u7 = FEATP[(size_t)c7 * ROWSTRIDE + LANEOFF]; \
        ACC16(u0) ACC16(u1) ACC16(u2) ACC16(u3) \
        ACC16(u4) ACC16(u5) ACC16(u6) ACC16(u7) \
        e += 8; \
    } \
    if (e + 4 <= end) { \
        int d0 = col[e], d1 = col[e + 1], d2 = col[e + 2], d3 = col[e + 3]; \
        uint4 u0 = FEATP[(size_t)d0 * ROWSTRIDE + LANEOFF]; \
        uint4 u1 = FEATP[(size_t)d1 * ROWSTRIDE + LANEOFF]; \
        uint4 u2 = FEATP[(size_t)d2 * ROWSTRIDE + LANEOFF]; \
        uint4 u3 = FEATP[(size_t)d3 * ROWSTRIDE + LANEOFF]; \
        ACC16(u0) ACC16(u1) ACC16(u2) ACC16(u3) \
        e += 4; \
    } \
    for (; e < end; ++e) { \
        uint4 u = FEATP[(size_t)col[e] * ROWSTRIDE + LANEOFF]; \
        ACC16(u) \
    }

// ---------------- fused agg layer 1 + bias + ReLU + GEMM2 (h2 = h1 @ W2, pre-scaled) ----
__global__ __launch_bounds__(256) void k_aggmg2(const uint4* __restrict__ feat,
                                                const int2* __restrict__ begend,
                                                const int* __restrict__ col,
                                                const float* __restrict__ dinv,
                                                const float* __restrict__ b1,
                                                const unsigned short* __restrict__ w2f,
                                                unsigned short* __restrict__ h2, int N) {
    __shared__ unsigned short lds[16 * 136];           // 16 h1 rows, stride 136 bf16
    __shared__ float dvs[16];                          // dinv of the 16 nodes
    const int grp = threadIdx.x >> 4;                  // 16 groups per block
    const int l16 = threadIdx.x & 15;
    const int node = blockIdx.x * 16 + grp;
    float a0 = 0.f, a1 = 0.f, a2 = 0.f, a3 = 0.f, a4 = 0.f, a5 = 0.f, a6 = 0.f, a7 = 0.f;
    if (node < N) {
        const float dd = dinv[node];
        if (l16 == 0) dvs[grp] = dd;
        const int2 be = begend[node];
        int e = be.x; const int end = be.y;
        {
            uint4 sv = feat[(size_t)node * 16 + l16];  // self-loop (row already * dinv[node])
            float2 q;
            q = bf2_to_f2(sv.x); a0 = q.x; a1 = q.y;
            q = bf2_to_f2(sv.y); a2 = q.x; a3 = q.y;
            q = bf2_to_f2(sv.z); a4 = q.x; a5 = q.y;
            q = bf2_to_f2(sv.w); a6 = q.x; a7 = q.y;
        }
        PIPE_GATHER8(feat, 16, l16)
        float4 ba = ((const float4*)b1)[2 * l16];
        float4 bb = ((const float4*)b1)[2 * l16 + 1];
        a0 = fmaxf(a0 * dd + ba.x, 0.0f);
        a1 = fmaxf(a1 * dd + ba.y, 0.0f);
        a2 = fmaxf(a2 * dd + ba.z, 0.0f);
        a3 = fmaxf(a3 * dd + ba.w, 0.0f);
        a4 = fmaxf(a4 * dd + bb.x, 0.0f);
        a5 = fmaxf(a5 * dd + bb.y, 0.0f);
        a6 = fmaxf(a6 * dd + bb.z, 0.0f);
        a7 = fmaxf(a7 * dd + bb.w, 0.0f);
    } else if (l16 == 0) dvs[grp] = 0.f;
    {   // stage h1 row to LDS (bf16)
        uint4 o;
        o.x = pack2(a0, a1);
        o.y = pack2(a2, a3);
        o.z = pack2(a4, a5);
        o.w = pack2(a6, a7);
        *(uint4*)&lds[grp * 136 + l16 * 8] = o;
    }
    __syncthreads();
    // ---- MFMA GEMM2 epilogue: 16x128 @ 128x64; wave w computes output col-tile w ----
    const int w = threadIdx.x >> 6, lane = threadIdx.x & 63;
    const int quad = lane >> 4, m = lane & 15;
    short8 a[4];
    #pragma unroll
    for (int ks = 0; ks < 4; ++ks)
        a[ks] = *(const short8*)&lds[m * 136 + ks * 32 + quad * 8];
    float4v acc = (float4v){0.f, 0.f, 0.f, 0.f};
    const short8* wf = (const short8*)w2f;
    #pragma unroll
    for (int ks = 0; ks < 4; ++ks)
        acc = __builtin_amdgcn_mfma_f32_16x16x32_bf16(a[ks], wf[(w * 4 + ks) * 64 + lane],
                                                      acc, 0, 0, 0);
    const int node0 = blockIdx.x * 16;
    #pragma unroll
    for (int r = 0; r < 4; ++r) {
        int gn = node0 + quad * 4 + r;                // C/D: col=lane&15, row=quad*4+reg
        if (gn < N) h2[(size_t)gn * 64 + w * 16 + m] = f2b(acc[r] * dvs[quad * 4 + r]);
    }
}

// ---------------- agg layer 2: one node per 8 lanes (uint4 gathers), +b2, fp32 out ----
__global__ __launch_bounds__(256) void k_agg64(const uint4* __restrict__ feat,
                                               const int2* __restrict__ begend,
                                               const int* __restrict__ col,
                                               const float* __restrict__ dinv,
                                               const float* __restrict__ bias,
                                               float* __restrict__ out, int N) {
    const int grp = threadIdx.x >> 3;                  // 32 nodes per block
    const int l8  = threadIdx.x & 7;
    const int node = blockIdx.x * 32 + grp;
    if (node >= N) return;
    const float dd = dinv[node];
    const int2 be = begend[node];
    int e = be.x; const int end = be.y;
    float a0, a1, a2, a3, a4, a5, a6, a7;
    {
        uint4 sv = feat[(size_t)node * 8 + l8];        // self-loop (pre-scaled)
        float2 q;
        q = bf2_to_f2(sv.x); a0 = q.x; a1 = q.y;
        q = bf2_to_f2(sv.y); a2 = q.x; a3 = q.y;
        q = bf2_to_f2(sv.z); a4 = q.x; a5 = q.y;
        q = bf2_to_f2(sv.w); a6 = q.x; a7 = q.y;
    }
    PIPE_GATHER8(feat, 8, l8)
    float4 ba = ((const float4*)bias)[2 * l8];
    float4 bb = ((const float4*)bias)[2 * l8 + 1];
    float4 o1, o2;
    o1.x = a0 * dd + ba.x;
    o1.y = a1 * dd + ba.y;
    o1.z = a2 * dd + ba.z;
    o1.w = a3 * dd + ba.w;
    o2.x = a4 * dd + bb.x;
    o2.y = a5 * dd + bb.y;
    o2.z = a6 * dd + bb.z;
    o2.w = a7 * dd + bb.w;
    float4* op = (float4*)out + (size_t)node * 16 + 2 * l8;
    op[0] = o1;
    op[1] = o2;
}

extern "C" void kernel_launch(void* const* d_in, const int* in_sizes, int n_in,
                              void* d_out, int out_size, void* d_ws, size_t ws_size,
                              hipStream_t stream) {
    const float* x  = (const float*)d_in[0];
    const int*   ei = (const int*)d_in[1];
    const float* W1 = (const float*)d_in[2];
    const float* b1 = (const float*)d_in[3];
    const float* W2 = (const float*)d_in[4];
    const float* b2 = (const float*)d_in[5];

    const int N = in_sizes[0] / IN_C;               // 50000
    const int E = in_sizes[1] / 2;                  // 800000
    const int NBK  = (N + BK - 1) / BK;             // 391 buckets
    const int NCHK = (E + 2047) / 2048;             // 391 edge chunks
    const int NT1  = (N + 63) / 64;                 // 782 GEMM tiles

    char* ws = (char*)d_ws;
    int*            bfill   = (int*)(ws + 64);
    int2*           begend  = (int2*)(ws + 4096);
    float*          dinv    = (float*)(ws + 404480);
    unsigned short* w1f     = (unsigned short*)(ws + 604672);
    unsigned short* w2f     = (unsigned short*)(ws + 637440);
    int*            ebuf    = (int*)(ws + 655360);               // NBK<<CAPLG packed ints
    int*            col     = (int*)(ws + 7061504);
    unsigned short* h       = (unsigned short*)(ws + 13467904);  // bf16 [N,128], pre-scaled
    unsigned short* h2      = (unsigned short*)(ws + 26267904);  // bf16 [N,64], pre-scaled

    // ---- bfill zero (graph-capture-legal async memset) ----
    hipMemsetAsync(bfill, 0, NBK * sizeof(int), stream);

    // ---- fused: edge partition + dtype probe | weight prep ----
    k_bpart<<<NCHK + 96, 256, 0, stream>>>(ei, bfill, ebuf, E, NBK, NCHK,
                                           W1, W2, w1f, w2f);

    // ---- fused: bucket-local CSR finalize + GEMM1 (h pre-scaled via local histogram) ----
    k_blmg1<<<NBK + NT1, 256, 0, stream>>>(ebuf, bfill, begend, dinv, col,
                                           x, w1f, h, N, NBK);

    // ---- fused layer-1 aggregation (+b1, ReLU) + GEMM2 MFMA epilogue ----
    k_aggmg2<<<(N + 15) / 16, 256, 0, stream>>>((const uint4*)h, begend, col, dinv, b1,
                                                w2f, h2, N);

    // ---- layer 2 aggregation (+b2, fp32 out) ----
    k_agg64<<<(N + 31) / 32, 256, 0, stream>>>((const uint4*)h2, begend, col, dinv, b2,
                                               (float*)d_out, N);
}

// Round 9
// 164.336 us; speedup vs baseline: 1.7978x; 1.0272x over previous
//
#include <hip/hip_runtime.h>
#include <hip/hip_bf16.h>

#define IN_C  128
#define HID_C 128
#define OUT_CC 64
#define BK    128           // nodes per bucket (dst >> 7)
#define CAPLG 12            // bucket capacity 4096 edges (mean 2046, >40 sigma)

using short8  = __attribute__((ext_vector_type(8))) short;
using float4v = __attribute__((ext_vector_type(4))) float;

// fp32 -> bf16 (round-to-nearest-even, finite inputs)
__device__ __forceinline__ unsigned short f2b(float f) {
    unsigned int u = __float_as_uint(f);
    return (unsigned short)((u + 0x7fffu + ((u >> 16) & 1u)) >> 16);
}
__device__ __forceinline__ unsigned int pack2(float a, float b) {
    return (unsigned int)f2b(a) | ((unsigned int)f2b(b) << 16);
}
__device__ __forceinline__ float2 bf2_to_f2(unsigned int v) {
    float2 r;
    r.x = __uint_as_float(v << 16);
    r.y = __uint_as_float(v & 0xffff0000u);
    return r;
}

// ---- ws layout (bytes) ----
// bfill     int[391]       @ 64         (zeroed via hipMemsetAsync)
// begend    int2[N]        @ 4096       (ends 404,096)
// dinv      float[N]       @ 404480     (ends 604,480)
// w1frag    bf16[16384]    @ 604672
// w2frag    bf16[8192]     @ 637440
// ebuf      int[391*4096]  @ 655360     (packed src|dlocal<<20; ends 7,061,504)
// col       int[391*4096]  @ 7061504    (ends 13,467,648)
// h (bf16)  [N*128]        @ 13467904   (pre-scaled by dinv[row]; ends 26,267,904)
// h2(bf16)  [N*64]         @ 26267904   (pre-scaled by dinv[row]; ends 32,667,904)

// ---------------- fused: edge partition (blocks < NCHK) | weight prep (rest) --------
__global__ __launch_bounds__(256) void k_bpart(const int* __restrict__ ei,
                                               int* __restrict__ bfill,
                                               int* __restrict__ ebuf, int E, int NBK,
                                               int NCHK,
                                               const float* __restrict__ W1,
                                               const float* __restrict__ W2,
                                               unsigned short* __restrict__ w1f,
                                               unsigned short* __restrict__ w2f) {
    const int t = threadIdx.x;
    if ((int)blockIdx.x >= NCHK) {                   // ---- weight prep blocks ----
        int e = ((int)blockIdx.x - NCHK) * 256 + t;
        if (e < 16384) {                             // W1: frag ((nt*4+ks)*64+lane)*8+j
            int j = e & 7, lane = (e >> 3) & 63, ks = (e >> 9) & 3, nt = e >> 11;
            int k = ks * 32 + ((lane >> 4) << 3) + j;
            int n = nt * 16 + (lane & 15);
            w1f[e] = f2b(W1[k * 128 + n]);
        } else if (e < 16384 + 8192) {
            int e2 = e - 16384;
            int j = e2 & 7, lane = (e2 >> 3) & 63, ks = (e2 >> 9) & 3, nt = e2 >> 11;
            int k = ks * 32 + ((lane >> 4) << 3) + j;
            int n = nt * 16 + (lane & 15);
            w2f[e2] = f2b(W2[k * 64 + n]);
        }
        return;
    }
    __shared__ int lh[512];
    __shared__ int lbase[512];
    __shared__ int s_st;
    for (int i = t; i < NBK; i += 256) lh[i] = 0;
    if (t < 64) {                                    // dtype probe (int64 vs int32)
        int ev = ei[2 * t], od = ei[2 * t + 1];
        unsigned long long onz = __ballot(od != 0);
        unsigned long long enz = __ballot(ev != 0);
        if (t == 0) s_st = (onz == 0ull && enz != 0ull) ? 2 : 1;
    }
    __syncthreads();
    const int st = s_st;
    const int base = blockIdx.x * 2048;
    int s[8], d[8];
    #pragma unroll
    for (int j = 0; j < 8; ++j) {
        int i = base + j * 256 + t;
        if (i < E) {
            s[j] = ei[(size_t)st * i];
            d[j] = ei[(size_t)st * ((size_t)E + i)];
            atomicAdd(&lh[d[j] >> 7], 1);
        } else d[j] = -1;
    }
    __syncthreads();
    for (int i = t; i < NBK; i += 256) {
        int c = lh[i];
        lbase[i] = c ? atomicAdd(&bfill[i], c) : 0;
        lh[i] = 0;                                   // becomes local rank counter
    }
    __syncthreads();
    #pragma unroll
    for (int j = 0; j < 8; ++j) {
        if (d[j] >= 0) {
            int b = d[j] >> 7;
            int r = lbase[b] + atomicAdd(&lh[b], 1);
            if (r < (1 << CAPLG))                    // statistical safety clamp
                ebuf[(b << CAPLG) + r] = s[j] | ((d[j] & (BK - 1)) << 20);
        }
    }
}

// ---------------- fused: per-bucket local CSR (blocks < NBK) | MFMA GEMM1 (rest) ----
__global__ __launch_bounds__(256) void k_blmg1(const int* __restrict__ ebuf,
                                               const int* __restrict__ bfill,
                                               int2* __restrict__ begend,
                                               float* __restrict__ dinv,
                                               int* __restrict__ col,
                                               const float* __restrict__ x,
                                               const unsigned short* __restrict__ w1f,
                                               unsigned short* __restrict__ h,
                                               int N, int NBK) {
    __shared__ unsigned short lds[64 * 136];          // 17.4 KB, shared by both paths
    __shared__ int cnt64[64];                         // GEMM path: local row degrees
    const int t = threadIdx.x;

    if ((int)blockIdx.x < NBK) {
        // ---- per-bucket CSR build ----
        int* cnt = (int*)lds;
        int* sc  = cnt + BK;
        int* off = sc + BK;
        const int n0 = blockIdx.x * BK;
        const int beg = (int)blockIdx.x << CAPLG;
        const int ecnt = min(bfill[blockIdx.x], 1 << CAPLG);
        if (t < BK) cnt[t] = 0;
        __syncthreads();
        for (int i = t; i < ecnt; i += 256)
            atomicAdd(&cnt[ebuf[beg + i] >> 20], 1);
        __syncthreads();
        if (t < BK) sc[t] = cnt[t];
        __syncthreads();
        for (int o = 1; o < BK; o <<= 1) {
            int v = (t < BK && t >= o) ? sc[t - o] : 0;
            __syncthreads();
            if (t < BK) sc[t] += v;
            __syncthreads();
        }
        if (t < BK) {
            int c = cnt[t];
            off[t] = sc[t] - c;                      // exclusive prefix
            if (n0 + t < N) {
                begend[n0 + t] = make_int2(beg + off[t], beg + sc[t]);
                dinv[n0 + t] = rsqrtf((float)c + 1.0f);
            }
            cnt[t] = 0;                              // becomes fill counter
        }
        __syncthreads();
        for (int i = t; i < ecnt; i += 256) {
            int e = ebuf[beg + i];
            int dl = e >> 20;
            int p = beg + off[dl] + atomicAdd(&cnt[dl], 1);
            col[p] = e & 0xFFFFF;
        }
        return;
    }

    // ---- MFMA GEMM1 tile ----
    const int tile = (int)blockIdx.x - NBK;
    const int row0 = tile * 64;
    const int bkt  = row0 >> 7;                       // owning bucket
    const int half = (row0 >> 6) & 1;                 // which 64-row half of the bucket
    if (t < 64) cnt64[t] = 0;
    __syncthreads();
    {   // local degree histogram: scan bucket's packed edges, filter to our half
        const int ebeg = bkt << CAPLG;
        const int ecnt = min(bfill[bkt], 1 << CAPLG);
        for (int i = t; i < ecnt; i += 256) {
            int dl = ebuf[ebeg + i] >> 20;
            if ((dl >> 6) == half) atomicAdd(&cnt64[dl & 63], 1);
        }
    }
    {   // stage x tile to LDS as bf16
        int r = t >> 2, cc = (t & 3) * 32;
        int grow = row0 + r;
        unsigned int* dst = (unsigned int*)&lds[r * 136 + cc];
        if (grow < N) {
            const float4* src = (const float4*)(x + (size_t)grow * 128 + cc);
            #pragma unroll
            for (int i = 0; i < 8; ++i) {
                float4 v = src[i];
                dst[2 * i]     = pack2(v.x, v.y);
                dst[2 * i + 1] = pack2(v.z, v.w);
            }
        } else {
            #pragma unroll
            for (int i = 0; i < 16; ++i) dst[i] = 0;
        }
    }
    __syncthreads();
    const int w = t >> 6, lane = t & 63;
    const int quad = lane >> 4, m = lane & 15;
    short8 a[4];
    #pragma unroll
    for (int ks = 0; ks < 4; ++ks)
        a[ks] = *(const short8*)&lds[(w * 16 + m) * 136 + ks * 32 + quad * 8];
    float4v acc[8];
    #pragma unroll
    for (int nt = 0; nt < 8; ++nt) acc[nt] = (float4v){0.f, 0.f, 0.f, 0.f};
    const short8* wf = (const short8*)w1f;
    #pragma unroll
    for (int nt = 0; nt < 8; ++nt)
        #pragma unroll
        for (int ks = 0; ks < 4; ++ks)
            acc[nt] = __builtin_amdgcn_mfma_f32_16x16x32_bf16(a[ks], wf[(nt * 4 + ks) * 64 + lane],
                                                              acc[nt], 0, 0, 0);
    float drr[4];
    #pragma unroll
    for (int r = 0; r < 4; ++r) {
        int lr = w * 16 + quad * 4 + r;               // local row in tile
        drr[r] = rsqrtf((float)cnt64[lr] + 1.0f);
    }
    #pragma unroll
    for (int nt = 0; nt < 8; ++nt)
        #pragma unroll
        for (int r = 0; r < 4; ++r) {
            int grow = row0 + w * 16 + quad * 4 + r;   // C/D: col=lane&15, row=quad*4+reg
            if (grow < N) h[(size_t)grow * 128 + nt * 16 + m] = f2b(acc[nt][r] * drr[r]);
        }
}

#define ACC16(u) { float2 q; \
    q = bf2_to_f2(u.x); a0 += q.x; a1 += q.y; \
    q = bf2_to_f2(u.y); a2 += q.x; a3 += q.y; \
    q = bf2_to_f2(u.z); a4 += q.x; a5 += q.y; \
    q = bf2_to_f2(u.w); a6 += q.x; a7 += q.y; }

// Stride-2 pipelined gather-sum: this lane-set handles edges e+sub, e+sub+2, ...
// 4 rows in flight + next-quad index prefetch; same per-lane register footprint as
// the round-3 4-wide loop, but each lane-set covers only HALF the node's edges.
#define PIPE_GATHER_S2(FEATP, ROWSTRIDE, LANEOFF) \
    int ee = e + sub; \
    int c0, c1, c2, c3; \
    if (ee + 6 < end) { c0 = col[ee]; c1 = col[ee + 2]; c2 = col[ee + 4]; c3 = col[ee + 6]; } \
    for (; ee + 14 < end; ee += 8) { \
        int p0 = col[ee + 8], p1 = col[ee + 10], p2 = col[ee + 12], p3 = col[ee + 14]; \
        uint4 u0 = FEATP[(size_t)c0 * ROWSTRIDE + LANEOFF]; \
        uint4 u1 = FEATP[(size_t)c1 * ROWSTRIDE + LANEOFF]; \
        uint4 u2 = FEATP[(size_t)c2 * ROWSTRIDE + LANEOFF]; \
        uint4 u3 = FEATP[(size_t)c3 * ROWSTRIDE + LANEOFF]; \
        ACC16(u0) ACC16(u1) ACC16(u2) ACC16(u3) \
        c0 = p0; c1 = p1; c2 = p2; c3 = p3; \
    } \
    if (ee + 6 < end) { \
        uint4 u0 = FEATP[(size_t)c0 * ROWSTRIDE + LANEOFF]; \
        uint4 u1 = FEATP[(size_t)c1 * ROWSTRIDE + LANEOFF]; \
        uint4 u2 = FEATP[(size_t)c2 * ROWSTRIDE + LANEOFF]; \
        uint4 u3 = FEATP[(size_t)c3 * ROWSTRIDE + LANEOFF]; \
        ACC16(u0) ACC16(u1) ACC16(u2) ACC16(u3) \
        ee += 8; \
    } \
    for (; ee < end; ee += 2) { \
        uint4 u = FEATP[(size_t)col[ee] * ROWSTRIDE + LANEOFF]; \
        ACC16(u) \
    }

// ---------------- fused agg layer 1 + bias + ReLU + GEMM2 (h2 = h1 @ W2, pre-scaled) ----
// 32 lanes per node: lanes 0-15 even-indexed edges, 16-31 odd; merged via shfl_xor(16).
// Halves per-lane loop trips at IDENTICAL per-lane VGPR (occupancy-neutral MLP boost).
__global__ __launch_bounds__(512) void k_aggmg2(const uint4* __restrict__ feat,
                                                const int2* __restrict__ begend,
                                                const int* __restrict__ col,
                                                const float* __restrict__ dinv,
                                                const float* __restrict__ b1,
                                                const unsigned short* __restrict__ w2f,
                                                unsigned short* __restrict__ h2, int N) {
    __shared__ unsigned short lds[16 * 136];           // 16 h1 rows, stride 136 bf16
    __shared__ float dvs[16];                          // dinv of the 16 nodes
    const int grp = threadIdx.x >> 5;                  // 16 nodes per 512-thread block
    const int l32 = threadIdx.x & 31;
    const int sub = l32 >> 4;                          // edge-parity lane-set
    const int l16 = l32 & 15;                          // channel slice
    const int node = blockIdx.x * 16 + grp;
    float a0 = 0.f, a1 = 0.f, a2 = 0.f, a3 = 0.f, a4 = 0.f, a5 = 0.f, a6 = 0.f, a7 = 0.f;
    if (node < N) {
        const float dd = dinv[node];
        if (l32 == 0) dvs[grp] = dd;
        const int2 be = begend[node];
        const int e = be.x, end = be.y;
        if (sub == 0) {                                // self-loop handled by even set
            uint4 sv = feat[(size_t)node * 16 + l16];  // (row already * dinv[node])
            ACC16(sv)
        }
        PIPE_GATHER_S2(feat, 16, l16)
        a0 += __shfl_xor(a0, 16); a1 += __shfl_xor(a1, 16);
        a2 += __shfl_xor(a2, 16); a3 += __shfl_xor(a3, 16);
        a4 += __shfl_xor(a4, 16); a5 += __shfl_xor(a5, 16);
        a6 += __shfl_xor(a6, 16); a7 += __shfl_xor(a7, 16);
        float4 ba = ((const float4*)b1)[2 * l16];
        float4 bb = ((const float4*)b1)[2 * l16 + 1];
        a0 = fmaxf(a0 * dd + ba.x, 0.0f);
        a1 = fmaxf(a1 * dd + ba.y, 0.0f);
        a2 = fmaxf(a2 * dd + ba.z, 0.0f);
        a3 = fmaxf(a3 * dd + ba.w, 0.0f);
        a4 = fmaxf(a4 * dd + bb.x, 0.0f);
        a5 = fmaxf(a5 * dd + bb.y, 0.0f);
        a6 = fmaxf(a6 * dd + bb.z, 0.0f);
        a7 = fmaxf(a7 * dd + bb.w, 0.0f);
    } else if (l32 == 0) dvs[grp] = 0.f;
    if (sub == 0) {                                    // stage h1 row to LDS (bf16)
        uint4 o;
        o.x = pack2(a0, a1);
        o.y = pack2(a2, a3);
        o.z = pack2(a4, a5);
        o.w = pack2(a6, a7);
        *(uint4*)&lds[grp * 136 + l16 * 8] = o;
    }
    __syncthreads();
    // ---- MFMA GEMM2 epilogue: 16x128 @ 128x64 on the first 4 waves ----
    if (threadIdx.x < 256) {
        const int w = threadIdx.x >> 6, lane = threadIdx.x & 63;
        const int quad = lane >> 4, m = lane & 15;
        short8 a[4];
        #pragma unroll
        for (int ks = 0; ks < 4; ++ks)
            a[ks] = *(const short8*)&lds[m * 136 + ks * 32 + quad * 8];
        float4v acc = (float4v){0.f, 0.f, 0.f, 0.f};
        const short8* wf = (const short8*)w2f;
        #pragma unroll
        for (int ks = 0; ks < 4; ++ks)
            acc = __builtin_amdgcn_mfma_f32_16x16x32_bf16(a[ks], wf[(w * 4 + ks) * 64 + lane],
                                                          acc, 0, 0, 0);
        const int node0 = blockIdx.x * 16;
        #pragma unroll
        for (int r = 0; r < 4; ++r) {
            int gn = node0 + quad * 4 + r;            // C/D: col=lane&15, row=quad*4+reg
            if (gn < N) h2[(size_t)gn * 64 + w * 16 + m] = f2b(acc[r] * dvs[quad * 4 + r]);
        }
    }
}

// ---------------- agg layer 2: 16 lanes per node (8 channels x 2 edge-parity sets) ----
__global__ __launch_bounds__(256) void k_agg64(const uint4* __restrict__ feat,
                                               const int2* __restrict__ begend,
                                               const int* __restrict__ col,
                                               const float* __restrict__ dinv,
                                               const float* __restrict__ bias,
                                               float* __restrict__ out, int N) {
    const int grp = threadIdx.x >> 4;                  // 16 nodes per block
    const int l16 = threadIdx.x & 15;
    const int sub = l16 >> 3;                          // edge-parity lane-set
    const int l8  = l16 & 7;                           // channel slice
    const int node = blockIdx.x * 16 + grp;
    if (node >= N) return;
    const float dd = dinv[node];
    const int2 be = begend[node];
    const int e = be.x, end = be.y;
    float a0 = 0.f, a1 = 0.f, a2 = 0.f, a3 = 0.f, a4 = 0.f, a5 = 0.f, a6 = 0.f, a7 = 0.f;
    if (sub == 0) {                                    // self-loop (pre-scaled)
        uint4 sv = feat[(size_t)node * 8 + l8];
        ACC16(sv)
    }
    PIPE_GATHER_S2(feat, 8, l8)
    a0 += __shfl_xor(a0, 8); a1 += __shfl_xor(a1, 8);
    a2 += __shfl_xor(a2, 8); a3 += __shfl_xor(a3, 8);
    a4 += __shfl_xor(a4, 8); a5 += __shfl_xor(a5, 8);
    a6 += __shfl_xor(a6, 8); a7 += __shfl_xor(a7, 8);
    if (sub == 0) {
        float4 ba = ((const float4*)bias)[2 * l8];
        float4 bb = ((const float4*)bias)[2 * l8 + 1];
        float4 o1, o2;
        o1.x = a0 * dd + ba.x;
        o1.y = a1 * dd + ba.y;
        o1.z = a2 * dd + ba.z;
        o1.w = a3 * dd + ba.w;
        o2.x = a4 * dd + bb.x;
        o2.y = a5 * dd + bb.y;
        o2.z = a6 * dd + bb.z;
        o2.w = a7 * dd + bb.w;
        float4* op = (float4*)out + (size_t)node * 16 + 2 * l8;
        op[0] = o1;
        op[1] = o2;
    }
}

extern "C" void kernel_launch(void* const* d_in, const int* in_sizes, int n_in,
                              void* d_out, int out_size, void* d_ws, size_t ws_size,
                              hipStream_t stream) {
    const float* x  = (const float*)d_in[0];
    const int*   ei = (const int*)d_in[1];
    const float* W1 = (const float*)d_in[2];
    const float* b1 = (const float*)d_in[3];
    const float* W2 = (const float*)d_in[4];
    const float* b2 = (const float*)d_in[5];

    const int N = in_sizes[0] / IN_C;               // 50000
    const int E = in_sizes[1] / 2;                  // 800000
    const int NBK  = (N + BK - 1) / BK;             // 391 buckets
    const int NCHK = (E + 2047) / 2048;             // 391 edge chunks
    const int NT1  = (N + 63) / 64;                 // 782 GEMM tiles

    char* ws = (char*)d_ws;
    int*            bfill   = (int*)(ws + 64);
    int2*           begend  = (int2*)(ws + 4096);
    float*          dinv    = (float*)(ws + 404480);
    unsigned short* w1f     = (unsigned short*)(ws + 604672);
    unsigned short* w2f     = (unsigned short*)(ws + 637440);
    int*            ebuf    = (int*)(ws + 655360);               // NBK<<CAPLG packed ints
    int*            col     = (int*)(ws + 7061504);
    unsigned short* h       = (unsigned short*)(ws + 13467904);  // bf16 [N,128], pre-scaled
    unsigned short* h2      = (unsigned short*)(ws + 26267904);  // bf16 [N,64], pre-scaled

    // ---- bfill zero (graph-capture-legal async memset) ----
    hipMemsetAsync(bfill, 0, NBK * sizeof(int), stream);

    // ---- fused: edge partition + dtype probe | weight prep ----
    k_bpart<<<NCHK + 96, 256, 0, stream>>>(ei, bfill, ebuf, E, NBK, NCHK,
                                           W1, W2, w1f, w2f);

    // ---- fused: bucket-local CSR finalize + GEMM1 (h pre-scaled via local histogram) ----
    k_blmg1<<<NBK + NT1, 256, 0, stream>>>(ebuf, bfill, begend, dinv, col,
                                           x, w1f, h, N, NBK);

    // ---- fused layer-1 aggregation (+b1, ReLU) + GEMM2 MFMA epilogue ----
    k_aggmg2<<<(N + 15) / 16, 512, 0, stream>>>((const uint4*)h, begend, col, dinv, b1,
                                                w2f, h2, N);

    // ---- layer 2 aggregation (+b2, fp32 out) ----
    k_agg64<<<(N + 15) / 16, 256, 0, stream>>>((const uint4*)h2, begend, col, dinv, b2,
                                               (float*)d_out, N);
}

// Round 10
// 162.814 us; speedup vs baseline: 1.8146x; 1.0093x over previous
//
#include <hip/hip_runtime.h>
#include <hip/hip_bf16.h>

#define IN_C  128
#define HID_C 128
#define OUT_CC 64
#define BK    128           // nodes per bucket (dst >> 7)
#define CAPLG 12            // bucket capacity 4096 edges (mean 2046, >40 sigma)

using short8  = __attribute__((ext_vector_type(8))) short;
using float4v = __attribute__((ext_vector_type(4))) float;

// fp32 -> bf16 (round-to-nearest-even, finite inputs)
__device__ __forceinline__ unsigned short f2b(float f) {
    unsigned int u = __float_as_uint(f);
    return (unsigned short)((u + 0x7fffu + ((u >> 16) & 1u)) >> 16);
}
__device__ __forceinline__ unsigned int pack2(float a, float b) {
    return (unsigned int)f2b(a) | ((unsigned int)f2b(b) << 16);
}
__device__ __forceinline__ float2 bf2_to_f2(unsigned int v) {
    float2 r;
    r.x = __uint_as_float(v << 16);
    r.y = __uint_as_float(v & 0xffff0000u);
    return r;
}

// ---- ws layout (bytes) ----
// bfill     int[391]       @ 64         (zeroed via hipMemsetAsync)
// begend    int2[N]        @ 4096       (ends 404,096)
// dinv      float[N]       @ 404480     (ends 604,480)
// w1frag    bf16[16384]    @ 604672
// w2frag    bf16[8192]     @ 637440
// ebuf      int[391*4096]  @ 655360     (packed src|dlocal<<20; ends 7,061,504)
// col       int[391*4096]  @ 7061504    (ends 13,467,648)
// h (bf16)  [N*128]        @ 13467904   (pre-scaled by dinv[row]; ends 26,267,904)
// h2(bf16)  [N*64]         @ 26267904   (pre-scaled by dinv[row]; ends 32,667,904)

// ---------------- fused: edge partition (blocks < NCHK) | weight prep (rest) --------
__global__ __launch_bounds__(256) void k_bpart(const int* __restrict__ ei,
                                               int* __restrict__ bfill,
                                               int* __restrict__ ebuf, int E, int NBK,
                                               int NCHK,
                                               const float* __restrict__ W1,
                                               const float* __restrict__ W2,
                                               unsigned short* __restrict__ w1f,
                                               unsigned short* __restrict__ w2f) {
    const int t = threadIdx.x;
    if ((int)blockIdx.x >= NCHK) {                   // ---- weight prep blocks ----
        int e = ((int)blockIdx.x - NCHK) * 256 + t;
        if (e < 16384) {                             // W1: frag ((nt*4+ks)*64+lane)*8+j
            int j = e & 7, lane = (e >> 3) & 63, ks = (e >> 9) & 3, nt = e >> 11;
            int k = ks * 32 + ((lane >> 4) << 3) + j;
            int n = nt * 16 + (lane & 15);
            w1f[e] = f2b(W1[k * 128 + n]);
        } else if (e < 16384 + 8192) {
            int e2 = e - 16384;
            int j = e2 & 7, lane = (e2 >> 3) & 63, ks = (e2 >> 9) & 3, nt = e2 >> 11;
            int k = ks * 32 + ((lane >> 4) << 3) + j;
            int n = nt * 16 + (lane & 15);
            w2f[e2] = f2b(W2[k * 64 + n]);
        }
        return;
    }
    __shared__ int lh[512];
    __shared__ int lbase[512];
    __shared__ int s_st;
    for (int i = t; i < NBK; i += 256) lh[i] = 0;
    if (t < 64) {                                    // dtype probe (int64 vs int32)
        int ev = ei[2 * t], od = ei[2 * t + 1];
        unsigned long long onz = __ballot(od != 0);
        unsigned long long enz = __ballot(ev != 0);
        if (t == 0) s_st = (onz == 0ull && enz != 0ull) ? 2 : 1;
    }
    __syncthreads();
    const int st = s_st;
    const int base = blockIdx.x * 2048;
    int s[8], d[8];
    #pragma unroll
    for (int j = 0; j < 8; ++j) {
        int i = base + j * 256 + t;
        if (i < E) {
            s[j] = ei[(size_t)st * i];
            d[j] = ei[(size_t)st * ((size_t)E + i)];
            atomicAdd(&lh[d[j] >> 7], 1);
        } else d[j] = -1;
    }
    __syncthreads();
    for (int i = t; i < NBK; i += 256) {
        int c = lh[i];
        lbase[i] = c ? atomicAdd(&bfill[i], c) : 0;
        lh[i] = 0;                                   // becomes local rank counter
    }
    __syncthreads();
    #pragma unroll
    for (int j = 0; j < 8; ++j) {
        if (d[j] >= 0) {
            int b = d[j] >> 7;
            int r = lbase[b] + atomicAdd(&lh[b], 1);
            if (r < (1 << CAPLG))                    // statistical safety clamp
                ebuf[(b << CAPLG) + r] = s[j] | ((d[j] & (BK - 1)) << 20);
        }
    }
}

// ---------------- fused: per-bucket local CSR (blocks < NBK) | MFMA GEMM1 (rest) ----
__global__ __launch_bounds__(256) void k_blmg1(const int* __restrict__ ebuf,
                                               const int* __restrict__ bfill,
                                               int2* __restrict__ begend,
                                               float* __restrict__ dinv,
                                               int* __restrict__ col,
                                               const float* __restrict__ x,
                                               const unsigned short* __restrict__ w1f,
                                               unsigned short* __restrict__ h,
                                               int N, int NBK) {
    __shared__ unsigned short lds[64 * 136];          // 17.4 KB, shared by both paths
    __shared__ int cnt64[64];                         // GEMM path: local row degrees
    const int t = threadIdx.x;

    if ((int)blockIdx.x < NBK) {
        // ---- per-bucket CSR build ----
        int* cnt = (int*)lds;
        int* sc  = cnt + BK;
        int* off = sc + BK;
        const int n0 = blockIdx.x * BK;
        const int beg = (int)blockIdx.x << CAPLG;
        const int ecnt = min(bfill[blockIdx.x], 1 << CAPLG);
        if (t < BK) cnt[t] = 0;
        __syncthreads();
        for (int i = t; i < ecnt; i += 256)
            atomicAdd(&cnt[ebuf[beg + i] >> 20], 1);
        __syncthreads();
        if (t < BK) sc[t] = cnt[t];
        __syncthreads();
        for (int o = 1; o < BK; o <<= 1) {
            int v = (t < BK && t >= o) ? sc[t - o] : 0;
            __syncthreads();
            if (t < BK) sc[t] += v;
            __syncthreads();
        }
        if (t < BK) {
            int c = cnt[t];
            off[t] = sc[t] - c;                      // exclusive prefix
            if (n0 + t < N) {
                begend[n0 + t] = make_int2(beg + off[t], beg + sc[t]);
                dinv[n0 + t] = rsqrtf((float)c + 1.0f);
            }
            cnt[t] = 0;                              // becomes fill counter
        }
        __syncthreads();
        for (int i = t; i < ecnt; i += 256) {
            int e = ebuf[beg + i];
            int dl = e >> 20;
            int p = beg + off[dl] + atomicAdd(&cnt[dl], 1);
            col[p] = e & 0xFFFFF;
        }
        return;
    }

    // ---- MFMA GEMM1 tile ----
    const int tile = (int)blockIdx.x - NBK;
    const int row0 = tile * 64;
    const int bkt  = row0 >> 7;                       // owning bucket
    const int half = (row0 >> 6) & 1;                 // which 64-row half of the bucket
    if (t < 64) cnt64[t] = 0;
    __syncthreads();
    {   // local degree histogram: scan bucket's packed edges, filter to our half
        const int ebeg = bkt << CAPLG;
        const int ecnt = min(bfill[bkt], 1 << CAPLG);
        for (int i = t; i < ecnt; i += 256) {
            int dl = ebuf[ebeg + i] >> 20;
            if ((dl >> 6) == half) atomicAdd(&cnt64[dl & 63], 1);
        }
    }
    {   // stage x tile to LDS as bf16
        int r = t >> 2, cc = (t & 3) * 32;
        int grow = row0 + r;
        unsigned int* dst = (unsigned int*)&lds[r * 136 + cc];
        if (grow < N) {
            const float4* src = (const float4*)(x + (size_t)grow * 128 + cc);
            #pragma unroll
            for (int i = 0; i < 8; ++i) {
                float4 v = src[i];
                dst[2 * i]     = pack2(v.x, v.y);
                dst[2 * i + 1] = pack2(v.z, v.w);
            }
        } else {
            #pragma unroll
            for (int i = 0; i < 16; ++i) dst[i] = 0;
        }
    }
    __syncthreads();
    const int w = t >> 6, lane = t & 63;
    const int quad = lane >> 4, m = lane & 15;
    short8 a[4];
    #pragma unroll
    for (int ks = 0; ks < 4; ++ks)
        a[ks] = *(const short8*)&lds[(w * 16 + m) * 136 + ks * 32 + quad * 8];
    float4v acc[8];
    #pragma unroll
    for (int nt = 0; nt < 8; ++nt) acc[nt] = (float4v){0.f, 0.f, 0.f, 0.f};
    const short8* wf = (const short8*)w1f;
    #pragma unroll
    for (int nt = 0; nt < 8; ++nt)
        #pragma unroll
        for (int ks = 0; ks < 4; ++ks)
            acc[nt] = __builtin_amdgcn_mfma_f32_16x16x32_bf16(a[ks], wf[(nt * 4 + ks) * 64 + lane],
                                                              acc[nt], 0, 0, 0);
    float drr[4];
    #pragma unroll
    for (int r = 0; r < 4; ++r) {
        int lr = w * 16 + quad * 4 + r;               // local row in tile
        drr[r] = rsqrtf((float)cnt64[lr] + 1.0f);
    }
    #pragma unroll
    for (int nt = 0; nt < 8; ++nt)
        #pragma unroll
        for (int r = 0; r < 4; ++r) {
            int grow = row0 + w * 16 + quad * 4 + r;   // C/D: col=lane&15, row=quad*4+reg
            if (grow < N) h[(size_t)grow * 128 + nt * 16 + m] = f2b(acc[nt][r] * drr[r]);
        }
}

#define ACC16(u) { float2 q; \
    q = bf2_to_f2(u.x); a0 += q.x; a1 += q.y; \
    q = bf2_to_f2(u.y); a2 += q.x; a3 += q.y; \
    q = bf2_to_f2(u.z); a4 += q.x; a5 += q.y; \
    q = bf2_to_f2(u.w); a6 += q.x; a7 += q.y; }

// 2-stage pipelined gather-sum over [e,end): col indices prefetched one quad ahead.
#define PIPE_GATHER(FEATP, ROWSTRIDE, LANEOFF) \
    int c0, c1, c2, c3; \
    if (e + 4 <= end) { c0 = col[e]; c1 = col[e + 1]; c2 = col[e + 2]; c3 = col[e + 3]; } \
    for (; e + 8 <= end; e += 4) { \
        int p0 = col[e + 4], p1 = col[e + 5], p2 = col[e + 6], p3 = col[e + 7]; \
        uint4 u0 = FEATP[(size_t)c0 * ROWSTRIDE + LANEOFF]; \
        uint4 u1 = FEATP[(size_t)c1 * ROWSTRIDE + LANEOFF]; \
        uint4 u2 = FEATP[(size_t)c2 * ROWSTRIDE + LANEOFF]; \
        uint4 u3 = FEATP[(size_t)c3 * ROWSTRIDE + LANEOFF]; \
        ACC16(u0) ACC16(u1) ACC16(u2) ACC16(u3) \
        c0 = p0; c1 = p1; c2 = p2; c3 = p3; \
    } \
    if (e + 4 <= end) { \
        uint4 u0 = FEATP[(size_t)c0 * ROWSTRIDE + LANEOFF]; \
        uint4 u1 = FEATP[(size_t)c1 * ROWSTRIDE + LANEOFF]; \
        uint4 u2 = FEATP[(size_t)c2 * ROWSTRIDE + LANEOFF]; \
        uint4 u3 = FEATP[(size_t)c3 * ROWSTRIDE + LANEOFF]; \
        ACC16(u0) ACC16(u1) ACC16(u2) ACC16(u3) \
        e += 4; \
    } \
    for (; e < end; ++e) { \
        uint4 u = FEATP[(size_t)col[e] * ROWSTRIDE + LANEOFF]; \
        ACC16(u) \
    }

// Stride-2 pipelined gather-sum: this lane-set handles edges e+sub, e+sub+2, ...
// (4 rows in flight + next-quad index prefetch; r9-verified loop structure.)
#define PIPE_GATHER_S2(FEATP, ROWSTRIDE, LANEOFF) \
    int ee = e + sub; \
    int c0, c1, c2, c3; \
    if (ee + 6 < end) { c0 = col[ee]; c1 = col[ee + 2]; c2 = col[ee + 4]; c3 = col[ee + 6]; } \
    for (; ee + 14 < end; ee += 8) { \
        int p0 = col[ee + 8], p1 = col[ee + 10], p2 = col[ee + 12], p3 = col[ee + 14]; \
        uint4 u0 = FEATP[(size_t)c0 * ROWSTRIDE + LANEOFF]; \
        uint4 u1 = FEATP[(size_t)c1 * ROWSTRIDE + LANEOFF]; \
        uint4 u2 = FEATP[(size_t)c2 * ROWSTRIDE + LANEOFF]; \
        uint4 u3 = FEATP[(size_t)c3 * ROWSTRIDE + LANEOFF]; \
        ACC16(u0) ACC16(u1) ACC16(u2) ACC16(u3) \
        c0 = p0; c1 = p1; c2 = p2; c3 = p3; \
    } \
    if (ee + 6 < end) { \
        uint4 u0 = FEATP[(size_t)c0 * ROWSTRIDE + LANEOFF]; \
        uint4 u1 = FEATP[(size_t)c1 * ROWSTRIDE + LANEOFF]; \
        uint4 u2 = FEATP[(size_t)c2 * ROWSTRIDE + LANEOFF]; \
        uint4 u3 = FEATP[(size_t)c3 * ROWSTRIDE + LANEOFF]; \
        ACC16(u0) ACC16(u1) ACC16(u2) ACC16(u3) \
        ee += 8; \
    } \
    for (; ee < end; ee += 2) { \
        uint4 u = FEATP[(size_t)col[ee] * ROWSTRIDE + LANEOFF]; \
        ACC16(u) \
    }

// ---------------- fused agg layer 1 + bias + ReLU + GEMM2 (h2 = h1 @ W2, pre-scaled) ----
// Cache-line-split aggregation: PASS A touches only the FIRST 128B line of every
// gathered row (channels 0-63; working set 6.4MB ~ L2-sized), PASS B the second.
// Within each pass, 8 even-edge lanes + 8 odd-edge lanes per node, shfl_xor(8) merge.
__global__ __launch_bounds__(256) void k_aggmg2(const uint4* __restrict__ feat,
                                                const int2* __restrict__ begend,
                                                const int* __restrict__ col,
                                                const float* __restrict__ dinv,
                                                const float* __restrict__ b1,
                                                const unsigned short* __restrict__ w2f,
                                                unsigned short* __restrict__ h2, int N) {
    __shared__ unsigned short lds[16 * 136];           // 16 h1 rows, stride 136 bf16
    __shared__ float dvs[16];                          // dinv of the 16 nodes
    const int grp = threadIdx.x >> 4;                  // 16 nodes per block
    const int l16 = threadIdx.x & 15;
    const int sub = l16 >> 3;                          // edge-parity lane-set
    const int l8  = l16 & 7;                           // channel octet in the 64-ch half
    const int node = blockIdx.x * 16 + grp;
    float dd = 0.f;
    int ebeg = 0, eend = 0;
    if (node < N) {
        dd = dinv[node];
        if (l16 == 0) dvs[grp] = dd;
        int2 be = begend[node];
        ebeg = be.x; eend = be.y;
    } else if (l16 == 0) dvs[grp] = 0.f;

    float a0 = 0.f, a1 = 0.f, a2 = 0.f, a3 = 0.f, a4 = 0.f, a5 = 0.f, a6 = 0.f, a7 = 0.f;
    // ---- PASS A: channels 0-63 (line 0 of each 256B row) ----
    if (node < N) {
        const int e = ebeg, end = eend;
        if (sub == 0) {                                // self-loop (row already * dinv[node])
            uint4 sv = feat[(size_t)node * 16 + l8];
            ACC16(sv)
        }
        { PIPE_GATHER_S2(feat, 16, l8) }
        a0 += __shfl_xor(a0, 8); a1 += __shfl_xor(a1, 8);
        a2 += __shfl_xor(a2, 8); a3 += __shfl_xor(a3, 8);
        a4 += __shfl_xor(a4, 8); a5 += __shfl_xor(a5, 8);
        a6 += __shfl_xor(a6, 8); a7 += __shfl_xor(a7, 8);
        float4 ba = ((const float4*)b1)[2 * l8];
        float4 bb = ((const float4*)b1)[2 * l8 + 1];
        a0 = fmaxf(a0 * dd + ba.x, 0.0f);
        a1 = fmaxf(a1 * dd + ba.y, 0.0f);
        a2 = fmaxf(a2 * dd + ba.z, 0.0f);
        a3 = fmaxf(a3 * dd + ba.w, 0.0f);
        a4 = fmaxf(a4 * dd + bb.x, 0.0f);
        a5 = fmaxf(a5 * dd + bb.y, 0.0f);
        a6 = fmaxf(a6 * dd + bb.z, 0.0f);
        a7 = fmaxf(a7 * dd + bb.w, 0.0f);
    }
    if (sub == 0) {                                    // lanes 0-7 store ch 0-63
        uint4 o;
        o.x = pack2(a0, a1);
        o.y = pack2(a2, a3);
        o.z = pack2(a4, a5);
        o.w = pack2(a6, a7);
        *(uint4*)&lds[grp * 136 + l8 * 8] = o;
    }
    // ---- PASS B: channels 64-127 (line 1 of each row) ----
    a0 = a1 = a2 = a3 = a4 = a5 = a6 = a7 = 0.f;
    if (node < N) {
        const int e = ebeg, end = eend;
        if (sub == 0) {
            uint4 sv = feat[(size_t)node * 16 + 8 + l8];
            ACC16(sv)
        }
        { PIPE_GATHER_S2(feat, 16, (8 + l8)) }
        a0 += __shfl_xor(a0, 8); a1 += __shfl_xor(a1, 8);
        a2 += __shfl_xor(a2, 8); a3 += __shfl_xor(a3, 8);
        a4 += __shfl_xor(a4, 8); a5 += __shfl_xor(a5, 8);
        a6 += __shfl_xor(a6, 8); a7 += __shfl_xor(a7, 8);
        float4 ba = ((const float4*)b1)[16 + 2 * l8];
        float4 bb = ((const float4*)b1)[17 + 2 * l8];
        a0 = fmaxf(a0 * dd + ba.x, 0.0f);
        a1 = fmaxf(a1 * dd + ba.y, 0.0f);
        a2 = fmaxf(a2 * dd + ba.z, 0.0f);
        a3 = fmaxf(a3 * dd + ba.w, 0.0f);
        a4 = fmaxf(a4 * dd + bb.x, 0.0f);
        a5 = fmaxf(a5 * dd + bb.y, 0.0f);
        a6 = fmaxf(a6 * dd + bb.z, 0.0f);
        a7 = fmaxf(a7 * dd + bb.w, 0.0f);
    }
    if (sub == 1) {                                    // lanes 8-15 store ch 64-127
        uint4 o;
        o.x = pack2(a0, a1);
        o.y = pack2(a2, a3);
        o.z = pack2(a4, a5);
        o.w = pack2(a6, a7);
        *(uint4*)&lds[grp * 136 + (8 + l8) * 8] = o;
    }
    __syncthreads();
    // ---- MFMA GEMM2 epilogue: 16x128 @ 128x64; wave w computes output col-tile w ----
    const int w = threadIdx.x >> 6, lane = threadIdx.x & 63;
    const int quad = lane >> 4, m = lane & 15;
    short8 a[4];
    #pragma unroll
    for (int ks = 0; ks < 4; ++ks)
        a[ks] = *(const short8*)&lds[m * 136 + ks * 32 + quad * 8];
    float4v acc = (float4v){0.f, 0.f, 0.f, 0.f};
    const short8* wf = (const short8*)w2f;
    #pragma unroll
    for (int ks = 0; ks < 4; ++ks)
        acc = __builtin_amdgcn_mfma_f32_16x16x32_bf16(a[ks], wf[(w * 4 + ks) * 64 + lane],
                                                      acc, 0, 0, 0);
    const int node0 = blockIdx.x * 16;
    #pragma unroll
    for (int r = 0; r < 4; ++r) {
        int gn = node0 + quad * 4 + r;                // C/D: col=lane&15, row=quad*4+reg
        if (gn < N) h2[(size_t)gn * 64 + w * 16 + m] = f2b(acc[r] * dvs[quad * 4 + r]);
    }
}

// ---------------- agg layer 2: one node per 8 lanes (uint4 gathers), +b2, fp32 out ----
__global__ __launch_bounds__(256) void k_agg64(const uint4* __restrict__ feat,
                                               const int2* __restrict__ begend,
                                               const int* __restrict__ col,
                                               const float* __restrict__ dinv,
                                               const float* __restrict__ bias,
                                               float* __restrict__ out, int N) {
    const int grp = threadIdx.x >> 3;                  // 32 nodes per block
    const int l8  = threadIdx.x & 7;
    const int node = blockIdx.x * 32 + grp;
    if (node >= N) return;
    const float dd = dinv[node];
    const int2 be = begend[node];
    int e = be.x; const int end = be.y;
    float a0, a1, a2, a3, a4, a5, a6, a7;
    {
        uint4 sv = feat[(size_t)node * 8 + l8];        // self-loop (pre-scaled)
        float2 q;
        q = bf2_to_f2(sv.x); a0 = q.x; a1 = q.y;
        q = bf2_to_f2(sv.y); a2 = q.x; a3 = q.y;
        q = bf2_to_f2(sv.z); a4 = q.x; a5 = q.y;
        q = bf2_to_f2(sv.w); a6 = q.x; a7 = q.y;
    }
    PIPE_GATHER(feat, 8, l8)
    float4 ba = ((const float4*)bias)[2 * l8];
    float4 bb = ((const float4*)bias)[2 * l8 + 1];
    float4 o1, o2;
    o1.x = a0 * dd + ba.x;
    o1.y = a1 * dd + ba.y;
    o1.z = a2 * dd + ba.z;
    o1.w = a3 * dd + ba.w;
    o2.x = a4 * dd + bb.x;
    o2.y = a5 * dd + bb.y;
    o2.z = a6 * dd + bb.z;
    o2.w = a7 * dd + bb.w;
    float4* op = (float4*)out + (size_t)node * 16 + 2 * l8;
    op[0] = o1;
    op[1] = o2;
}

extern "C" void kernel_launch(void* const* d_in, const int* in_sizes, int n_in,
                              void* d_out, int out_size, void* d_ws, size_t ws_size,
                              hipStream_t stream) {
    const float* x  = (const float*)d_in[0];
    const int*   ei = (const int*)d_in[1];
    const float* W1 = (const float*)d_in[2];
    const float* b1 = (const float*)d_in[3];
    const float* W2 = (const float*)d_in[4];
    const float* b2 = (const float*)d_in[5];

    const int N = in_sizes[0] / IN_C;               // 50000
    const int E = in_sizes[1] / 2;                  // 800000
    const int NBK  = (N + BK - 1) / BK;             // 391 buckets
    const int NCHK = (E + 2047) / 2048;             // 391 edge chunks
    const int NT1  = (N + 63) / 64;                 // 782 GEMM tiles

    char* ws = (char*)d_ws;
    int*            bfill   = (int*)(ws + 64);
    int2*           begend  = (int2*)(ws + 4096);
    float*          dinv    = (float*)(ws + 404480);
    unsigned short* w1f     = (unsigned short*)(ws + 604672);
    unsigned short* w2f     = (unsigned short*)(ws + 637440);
    int*            ebuf    = (int*)(ws + 655360);               // NBK<<CAPLG packed ints
    int*            col     = (int*)(ws + 7061504);
    unsigned short* h       = (unsigned short*)(ws + 13467904);  // bf16 [N,128], pre-scaled
    unsigned short* h2      = (unsigned short*)(ws + 26267904);  // bf16 [N,64], pre-scaled

    // ---- bfill zero (graph-capture-legal async memset) ----
    hipMemsetAsync(bfill, 0, NBK * sizeof(int), stream);

    // ---- fused: edge partition + dtype probe | weight prep ----
    k_bpart<<<NCHK + 96, 256, 0, stream>>>(ei, bfill, ebuf, E, NBK, NCHK,
                                           W1, W2, w1f, w2f);

    // ---- fused: bucket-local CSR finalize + GEMM1 (h pre-scaled via local histogram) ----
    k_blmg1<<<NBK + NT1, 256, 0, stream>>>(ebuf, bfill, begend, dinv, col,
                                           x, w1f, h, N, NBK);

    // ---- fused layer-1 aggregation (line-split, +b1, ReLU) + GEMM2 MFMA epilogue ----
    k_aggmg2<<<(N + 15) / 16, 256, 0, stream>>>((const uint4*)h, begend, col, dinv, b1,
                                                w2f, h2, N);

    // ---- layer 2 aggregation (+b2, fp32 out) ----
    k_agg64<<<(N + 31) / 32, 256, 0, stream>>>((const uint4*)h2, begend, col, dinv, b2,
                                               (float*)d_out, N);
}

// Round 11
// 161.844 us; speedup vs baseline: 1.8255x; 1.0060x over previous
//
#include <hip/hip_runtime.h>
#include <hip/hip_bf16.h>

#define IN_C  128
#define HID_C 128
#define OUT_CC 64
#define BK    128           // nodes per bucket (dst >> 7)
#define CAPLG 12            // bucket capacity 4096 edges (mean 2046, >40 sigma)

using short8  = __attribute__((ext_vector_type(8))) short;
using float4v = __attribute__((ext_vector_type(4))) float;

// fp32 -> bf16 (round-to-nearest-even, finite inputs)
__device__ __forceinline__ unsigned short f2b(float f) {
    unsigned int u = __float_as_uint(f);
    return (unsigned short)((u + 0x7fffu + ((u >> 16) & 1u)) >> 16);
}
__device__ __forceinline__ unsigned int pack2(float a, float b) {
    return (unsigned int)f2b(a) | ((unsigned int)f2b(b) << 16);
}
__device__ __forceinline__ float2 bf2_to_f2(unsigned int v) {
    float2 r;
    r.x = __uint_as_float(v << 16);
    r.y = __uint_as_float(v & 0xffff0000u);
    return r;
}

// ---- ws layout (bytes) ----
// bfill     int[391]       @ 64         (zeroed via hipMemsetAsync)
// begend    int2[N]        @ 4096       (ends 404,096)
// dinv      float[N]       @ 404480     (ends 604,480)
// w1frag    bf16[16384]    @ 604672
// w2frag    bf16[8192]     @ 637440
// ebuf      int[391*4096]  @ 655360     (packed src|dlocal<<20; ends 7,061,504)
// col       int[391*4096]  @ 7061504    (ends 13,467,648)
// h (bf16)  [N*128]        @ 13467904   (pre-scaled by dinv[row]; ends 26,267,904)
// h2(bf16)  [N*64]         @ 26267904   (pre-scaled by dinv[row]; ends 32,667,904)

// ---------------- fused: edge partition (blocks < NCHK) | weight prep (rest) --------
__global__ __launch_bounds__(256) void k_bpart(const int* __restrict__ ei,
                                               int* __restrict__ bfill,
                                               int* __restrict__ ebuf, int E, int NBK,
                                               int NCHK,
                                               const float* __restrict__ W1,
                                               const float* __restrict__ W2,
                                               unsigned short* __restrict__ w1f,
                                               unsigned short* __restrict__ w2f) {
    const int t = threadIdx.x;
    if ((int)blockIdx.x >= NCHK) {                   // ---- weight prep blocks ----
        int e = ((int)blockIdx.x - NCHK) * 256 + t;
        if (e < 16384) {                             // W1: frag ((nt*4+ks)*64+lane)*8+j
            int j = e & 7, lane = (e >> 3) & 63, ks = (e >> 9) & 3, nt = e >> 11;
            int k = ks * 32 + ((lane >> 4) << 3) + j;
            int n = nt * 16 + (lane & 15);
            w1f[e] = f2b(W1[k * 128 + n]);
        } else if (e < 16384 + 8192) {
            int e2 = e - 16384;
            int j = e2 & 7, lane = (e2 >> 3) & 63, ks = (e2 >> 9) & 3, nt = e2 >> 11;
            int k = ks * 32 + ((lane >> 4) << 3) + j;
            int n = nt * 16 + (lane & 15);
            w2f[e2] = f2b(W2[k * 64 + n]);
        }
        return;
    }
    __shared__ int lh[512];
    __shared__ int lbase[512];
    __shared__ int s_st;
    for (int i = t; i < NBK; i += 256) lh[i] = 0;
    if (t < 64) {                                    // dtype probe (int64 vs int32)
        int ev = ei[2 * t], od = ei[2 * t + 1];
        unsigned long long onz = __ballot(od != 0);
        unsigned long long enz = __ballot(ev != 0);
        if (t == 0) s_st = (onz == 0ull && enz != 0ull) ? 2 : 1;
    }
    __syncthreads();
    const int st = s_st;
    const int base = blockIdx.x * 2048;
    int s[8], d[8];
    #pragma unroll
    for (int j = 0; j < 8; ++j) {
        int i = base + j * 256 + t;
        if (i < E) {
            s[j] = ei[(size_t)st * i];
            d[j] = ei[(size_t)st * ((size_t)E + i)];
            atomicAdd(&lh[d[j] >> 7], 1);
        } else d[j] = -1;
    }
    __syncthreads();
    for (int i = t; i < NBK; i += 256) {
        int c = lh[i];
        lbase[i] = c ? atomicAdd(&bfill[i], c) : 0;
        lh[i] = 0;                                   // becomes local rank counter
    }
    __syncthreads();
    #pragma unroll
    for (int j = 0; j < 8; ++j) {
        if (d[j] >= 0) {
            int b = d[j] >> 7;
            int r = lbase[b] + atomicAdd(&lh[b], 1);
            if (r < (1 << CAPLG))                    // statistical safety clamp
                ebuf[(b << CAPLG) + r] = s[j] | ((d[j] & (BK - 1)) << 20);
        }
    }
}

// ---------------- fused: per-bucket local CSR (blocks < NBK) | MFMA GEMM1 (rest) ----
__global__ __launch_bounds__(256) void k_blmg1(const int* __restrict__ ebuf,
                                               const int* __restrict__ bfill,
                                               int2* __restrict__ begend,
                                               float* __restrict__ dinv,
                                               int* __restrict__ col,
                                               const float* __restrict__ x,
                                               const unsigned short* __restrict__ w1f,
                                               unsigned short* __restrict__ h,
                                               int N, int NBK) {
    __shared__ unsigned short lds[64 * 136];          // 17.4 KB, shared by both paths
    __shared__ int cnt64[64];                         // GEMM path: local row degrees
    const int t = threadIdx.x;

    if ((int)blockIdx.x < NBK) {
        // ---- per-bucket CSR build ----
        int* cnt = (int*)lds;
        int* sc  = cnt + BK;
        int* off = sc + BK;
        const int n0 = blockIdx.x * BK;
        const int beg = (int)blockIdx.x << CAPLG;
        const int ecnt = min(bfill[blockIdx.x], 1 << CAPLG);
        if (t < BK) cnt[t] = 0;
        __syncthreads();
        for (int i = t; i < ecnt; i += 256)
            atomicAdd(&cnt[ebuf[beg + i] >> 20], 1);
        __syncthreads();
        if (t < BK) sc[t] = cnt[t];
        __syncthreads();
        for (int o = 1; o < BK; o <<= 1) {
            int v = (t < BK && t >= o) ? sc[t - o] : 0;
            __syncthreads();
            if (t < BK) sc[t] += v;
            __syncthreads();
        }
        if (t < BK) {
            int c = cnt[t];
            off[t] = sc[t] - c;                      // exclusive prefix
            if (n0 + t < N) {
                begend[n0 + t] = make_int2(beg + off[t], beg + sc[t]);
                dinv[n0 + t] = rsqrtf((float)c + 1.0f);
            }
            cnt[t] = 0;                              // becomes fill counter
        }
        __syncthreads();
        for (int i = t; i < ecnt; i += 256) {
            int e = ebuf[beg + i];
            int dl = e >> 20;
            int p = beg + off[dl] + atomicAdd(&cnt[dl], 1);
            col[p] = e & 0xFFFFF;
        }
        return;
    }

    // ---- MFMA GEMM1 tile ----
    const int tile = (int)blockIdx.x - NBK;
    const int row0 = tile * 64;
    const int bkt  = row0 >> 7;                       // owning bucket
    const int half = (row0 >> 6) & 1;                 // which 64-row half of the bucket
    if (t < 64) cnt64[t] = 0;
    __syncthreads();
    {   // local degree histogram: scan bucket's packed edges, filter to our half
        const int ebeg = bkt << CAPLG;
        const int ecnt = min(bfill[bkt], 1 << CAPLG);
        for (int i = t; i < ecnt; i += 256) {
            int dl = ebuf[ebeg + i] >> 20;
            if ((dl >> 6) == half) atomicAdd(&cnt64[dl & 63], 1);
        }
    }
    {   // stage x tile to LDS as bf16
        int r = t >> 2, cc = (t & 3) * 32;
        int grow = row0 + r;
        unsigned int* dst = (unsigned int*)&lds[r * 136 + cc];
        if (grow < N) {
            const float4* src = (const float4*)(x + (size_t)grow * 128 + cc);
            #pragma unroll
            for (int i = 0; i < 8; ++i) {
                float4 v = src[i];
                dst[2 * i]     = pack2(v.x, v.y);
                dst[2 * i + 1] = pack2(v.z, v.w);
            }
        } else {
            #pragma unroll
            for (int i = 0; i < 16; ++i) dst[i] = 0;
        }
    }
    __syncthreads();
    const int w = t >> 6, lane = t & 63;
    const int quad = lane >> 4, m = lane & 15;
    short8 a[4];
    #pragma unroll
    for (int ks = 0; ks < 4; ++ks)
        a[ks] = *(const short8*)&lds[(w * 16 + m) * 136 + ks * 32 + quad * 8];
    float4v acc[8];
    #pragma unroll
    for (int nt = 0; nt < 8; ++nt) acc[nt] = (float4v){0.f, 0.f, 0.f, 0.f};
    const short8* wf = (const short8*)w1f;
    #pragma unroll
    for (int nt = 0; nt < 8; ++nt)
        #pragma unroll
        for (int ks = 0; ks < 4; ++ks)
            acc[nt] = __builtin_amdgcn_mfma_f32_16x16x32_bf16(a[ks], wf[(nt * 4 + ks) * 64 + lane],
                                                              acc[nt], 0, 0, 0);
    float drr[4];
    #pragma unroll
    for (int r = 0; r < 4; ++r) {
        int lr = w * 16 + quad * 4 + r;               // local row in tile
        drr[r] = rsqrtf((float)cnt64[lr] + 1.0f);
    }
    #pragma unroll
    for (int nt = 0; nt < 8; ++nt)
        #pragma unroll
        for (int r = 0; r < 4; ++r) {
            int grow = row0 + w * 16 + quad * 4 + r;   // C/D: col=lane&15, row=quad*4+reg
            if (grow < N) h[(size_t)grow * 128 + nt * 16 + m] = f2b(acc[nt][r] * drr[r]);
        }
}

#define ACC16(u) { float2 q; \
    q = bf2_to_f2(u.x); a0 += q.x; a1 += q.y; \
    q = bf2_to_f2(u.y); a2 += q.x; a3 += q.y; \
    q = bf2_to_f2(u.z); a4 += q.x; a5 += q.y; \
    q = bf2_to_f2(u.w); a6 += q.x; a7 += q.y; }

// 2-stage pipelined gather-sum over [e,end): col indices prefetched one quad ahead.
#define PIPE_GATHER(FEATP, ROWSTRIDE, LANEOFF) \
    int c0, c1, c2, c3; \
    if (e + 4 <= end) { c0 = col[e]; c1 = col[e + 1]; c2 = col[e + 2]; c3 = col[e + 3]; } \
    for (; e + 8 <= end; e += 4) { \
        int p0 = col[e + 4], p1 = col[e + 5], p2 = col[e + 6], p3 = col[e + 7]; \
        uint4 u0 = FEATP[(size_t)c0 * ROWSTRIDE + LANEOFF]; \
        uint4 u1 = FEATP[(size_t)c1 * ROWSTRIDE + LANEOFF]; \
        uint4 u2 = FEATP[(size_t)c2 * ROWSTRIDE + LANEOFF]; \
        uint4 u3 = FEATP[(size_t)c3 * ROWSTRIDE + LANEOFF]; \
        ACC16(u0) ACC16(u1) ACC16(u2) ACC16(u3) \
        c0 = p0; c1 = p1; c2 = p2; c3 = p3; \
    } \
    if (e + 4 <= end) { \
        uint4 u0 = FEATP[(size_t)c0 * ROWSTRIDE + LANEOFF]; \
        uint4 u1 = FEATP[(size_t)c1 * ROWSTRIDE + LANEOFF]; \
        uint4 u2 = FEATP[(size_t)c2 * ROWSTRIDE + LANEOFF]; \
        uint4 u3 = FEATP[(size_t)c3 * ROWSTRIDE + LANEOFF]; \
        ACC16(u0) ACC16(u1) ACC16(u2) ACC16(u3) \
        e += 4; \
    } \
    for (; e < end; ++e) { \
        uint4 u = FEATP[(size_t)col[e] * ROWSTRIDE + LANEOFF]; \
        ACC16(u) \
    }

// ---------------- fused agg layer 1 + bias + ReLU + GEMM2 (h2 = h1 @ W2, pre-scaled) ----
__global__ __launch_bounds__(256) void k_aggmg2(const uint4* __restrict__ feat,
                                                const int2* __restrict__ begend,
                                                const int* __restrict__ col,
                                                const float* __restrict__ dinv,
                                                const float* __restrict__ b1,
                                                const unsigned short* __restrict__ w2f,
                                                unsigned short* __restrict__ h2, int N) {
    __shared__ unsigned short lds[16 * 136];           // 16 h1 rows, stride 136 bf16
    __shared__ float dvs[16];                          // dinv of the 16 nodes
    const int grp = threadIdx.x >> 4;                  // 16 groups per block
    const int l16 = threadIdx.x & 15;
    const int node = blockIdx.x * 16 + grp;
    float a0 = 0.f, a1 = 0.f, a2 = 0.f, a3 = 0.f, a4 = 0.f, a5 = 0.f, a6 = 0.f, a7 = 0.f;
    if (node < N) {
        const float dd = dinv[node];
        if (l16 == 0) dvs[grp] = dd;
        const int2 be = begend[node];
        int e = be.x; const int end = be.y;
        {
            uint4 sv = feat[(size_t)node * 16 + l16];  // self-loop (row already * dinv[node])
            float2 q;
            q = bf2_to_f2(sv.x); a0 = q.x; a1 = q.y;
            q = bf2_to_f2(sv.y); a2 = q.x; a3 = q.y;
            q = bf2_to_f2(sv.z); a4 = q.x; a5 = q.y;
            q = bf2_to_f2(sv.w); a6 = q.x; a7 = q.y;
        }
        PIPE_GATHER(feat, 16, l16)
        float4 ba = ((const float4*)b1)[2 * l16];
        float4 bb = ((const float4*)b1)[2 * l16 + 1];
        a0 = fmaxf(a0 * dd + ba.x, 0.0f);
        a1 = fmaxf(a1 * dd + ba.y, 0.0f);
        a2 = fmaxf(a2 * dd + ba.z, 0.0f);
        a3 = fmaxf(a3 * dd + ba.w, 0.0f);
        a4 = fmaxf(a4 * dd + bb.x, 0.0f);
        a5 = fmaxf(a5 * dd + bb.y, 0.0f);
        a6 = fmaxf(a6 * dd + bb.z, 0.0f);
        a7 = fmaxf(a7 * dd + bb.w, 0.0f);
    } else if (l16 == 0) dvs[grp] = 0.f;
    {   // stage h1 row to LDS (bf16)
        uint4 o;
        o.x = pack2(a0, a1);
        o.y = pack2(a2, a3);
        o.z = pack2(a4, a5);
        o.w = pack2(a6, a7);
        *(uint4*)&lds[grp * 136 + l16 * 8] = o;
    }
    __syncthreads();
    // ---- MFMA GEMM2 epilogue: 16x128 @ 128x64; wave w computes output col-tile w ----
    const int w = threadIdx.x >> 6, lane = threadIdx.x & 63;
    const int quad = lane >> 4, m = lane & 15;
    short8 a[4];
    #pragma unroll
    for (int ks = 0; ks < 4; ++ks)
        a[ks] = *(const short8*)&lds[m * 136 + ks * 32 + quad * 8];
    float4v acc = (float4v){0.f, 0.f, 0.f, 0.f};
    const short8* wf = (const short8*)w2f;
    #pragma unroll
    for (int ks = 0; ks < 4; ++ks)
        acc = __builtin_amdgcn_mfma_f32_16x16x32_bf16(a[ks], wf[(w * 4 + ks) * 64 + lane],
                                                      acc, 0, 0, 0);
    const int node0 = blockIdx.x * 16;
    #pragma unroll
    for (int r = 0; r < 4; ++r) {
        int gn = node0 + quad * 4 + r;                // C/D: col=lane&15, row=quad*4+reg
        if (gn < N) h2[(size_t)gn * 64 + w * 16 + m] = f2b(acc[r] * dvs[quad * 4 + r]);
    }
}

// ---------------- agg layer 2: one node per 8 lanes (uint4 gathers), +b2, fp32 out ----
__global__ __launch_bounds__(256) void k_agg64(const uint4* __restrict__ feat,
                                               const int2* __restrict__ begend,
                                               const int* __restrict__ col,
                                               const float* __restrict__ dinv,
                                               const float* __restrict__ bias,
                                               float* __restrict__ out, int N) {
    const int grp = threadIdx.x >> 3;                  // 32 nodes per block
    const int l8  = threadIdx.x & 7;
    const int node = blockIdx.x * 32 + grp;
    if (node >= N) return;
    const float dd = dinv[node];
    const int2 be = begend[node];
    int e = be.x; const int end = be.y;
    float a0, a1, a2, a3, a4, a5, a6, a7;
    {
        uint4 sv = feat[(size_t)node * 8 + l8];        // self-loop (pre-scaled)
        float2 q;
        q = bf2_to_f2(sv.x); a0 = q.x; a1 = q.y;
        q = bf2_to_f2(sv.y); a2 = q.x; a3 = q.y;
        q = bf2_to_f2(sv.z); a4 = q.x; a5 = q.y;
        q = bf2_to_f2(sv.w); a6 = q.x; a7 = q.y;
    }
    PIPE_GATHER(feat, 8, l8)
    float4 ba = ((const float4*)bias)[2 * l8];
    float4 bb = ((const float4*)bias)[2 * l8 + 1];
    float4 o1, o2;
    o1.x = a0 * dd + ba.x;
    o1.y = a1 * dd + ba.y;
    o1.z = a2 * dd + ba.z;
    o1.w = a3 * dd + ba.w;
    o2.x = a4 * dd + bb.x;
    o2.y = a5 * dd + bb.y;
    o2.z = a6 * dd + bb.z;
    o2.w = a7 * dd + bb.w;
    float4* op = (float4*)out + (size_t)node * 16 + 2 * l8;
    op[0] = o1;
    op[1] = o2;
}

extern "C" void kernel_launch(void* const* d_in, const int* in_sizes, int n_in,
                              void* d_out, int out_size, void* d_ws, size_t ws_size,
                              hipStream_t stream) {
    const float* x  = (const float*)d_in[0];
    const int*   ei = (const int*)d_in[1];
    const float* W1 = (const float*)d_in[2];
    const float* b1 = (const float*)d_in[3];
    const float* W2 = (const float*)d_in[4];
    const float* b2 = (const float*)d_in[5];

    const int N = in_sizes[0] / IN_C;               // 50000
    const int E = in_sizes[1] / 2;                  // 800000
    const int NBK  = (N + BK - 1) / BK;             // 391 buckets
    const int NCHK = (E + 2047) / 2048;             // 391 edge chunks
    const int NT1  = (N + 63) / 64;                 // 782 GEMM tiles

    char* ws = (char*)d_ws;
    int*            bfill   = (int*)(ws + 64);
    int2*           begend  = (int2*)(ws + 4096);
    float*          dinv    = (float*)(ws + 404480);
    unsigned short* w1f     = (unsigned short*)(ws + 604672);
    unsigned short* w2f     = (unsigned short*)(ws + 637440);
    int*            ebuf    = (int*)(ws + 655360);               // NBK<<CAPLG packed ints
    int*            col     = (int*)(ws + 7061504);
    unsigned short* h       = (unsigned short*)(ws + 13467904);  // bf16 [N,128], pre-scaled
    unsigned short* h2      = (unsigned short*)(ws + 26267904);  // bf16 [N,64], pre-scaled

    // ---- bfill zero (graph-capture-legal async memset) ----
    hipMemsetAsync(bfill, 0, NBK * sizeof(int), stream);

    // ---- fused: edge partition + dtype probe | weight prep ----
    k_bpart<<<NCHK + 96, 256, 0, stream>>>(ei, bfill, ebuf, E, NBK, NCHK,
                                           W1, W2, w1f, w2f);

    // ---- fused: bucket-local CSR finalize + GEMM1 (h pre-scaled via local histogram) ----
    k_blmg1<<<NBK + NT1, 256, 0, stream>>>(ebuf, bfill, begend, dinv, col,
                                           x, w1f, h, N, NBK);

    // ---- fused layer-1 aggregation (+b1, ReLU) + GEMM2 MFMA epilogue ----
    k_aggmg2<<<(N + 15) / 16, 256, 0, stream>>>((const uint4*)h, begend, col, dinv, b1,
                                                w2f, h2, N);

    // ---- layer 2 aggregation (+b2, fp32 out) ----
    k_agg64<<<(N + 31) / 32, 256, 0, stream>>>((const uint4*)h2, begend, col, dinv, b2,
                                               (float*)d_out, N);
}